// Round 1
// baseline (731.542 us; speedup 1.0000x reference)
//
#include <hip/hip_runtime.h>
#include <math.h>

#define NNODES 50000
#define NEDGES 800000

// ---------------- CSR build ----------------

__global__ __launch_bounds__(256) void k_deg(const int* __restrict__ ei, int* __restrict__ deg) {
    int e = blockIdx.x * 256 + threadIdx.x;
    if (e < NEDGES) atomicAdd(&deg[ei[NEDGES + e]], 1);
}

__global__ __launch_bounds__(256) void k_scanA(const int* __restrict__ deg, int* __restrict__ incl,
                                               int* __restrict__ partial) {
    int t = threadIdx.x;
    int i = blockIdx.x * 256 + t;
    int v = (i < NNODES) ? deg[i] : 0;
    int lane = t & 63, wid = t >> 6;
    int s = v;
#pragma unroll
    for (int d = 1; d < 64; d <<= 1) { int u = __shfl_up(s, d, 64); if (lane >= d) s += u; }
    __shared__ int wtot[4];
    if (lane == 63) wtot[wid] = s;
    __syncthreads();
    int off = 0;
    for (int w = 0; w < wid; ++w) off += wtot[w];
    s += off;
    if (i < NNODES) incl[i] = s;
    if (t == 255) partial[blockIdx.x] = s;
}

__global__ __launch_bounds__(256) void k_scanB(const int* __restrict__ partial, int* __restrict__ chunkoff,
                                               int nch) {
    int t = threadIdx.x;
    int v = (t < nch) ? partial[t] : 0;
    int lane = t & 63, wid = t >> 6;
    int s = v;
#pragma unroll
    for (int d = 1; d < 64; d <<= 1) { int u = __shfl_up(s, d, 64); if (lane >= d) s += u; }
    __shared__ int wtot[4];
    if (lane == 63) wtot[wid] = s;
    __syncthreads();
    int off = 0;
    for (int w = 0; w < wid; ++w) off += wtot[w];
    s += off;
    if (t < nch) chunkoff[t] = s - v;  // exclusive
}

__global__ __launch_bounds__(256) void k_scanC(const int* __restrict__ deg, const int* __restrict__ incl,
                                               const int* __restrict__ chunkoff, int* __restrict__ rowst,
                                               int* __restrict__ cursor) {
    int i = blockIdx.x * 256 + threadIdx.x;
    if (i < NNODES) {
        int rs1 = incl[i] + chunkoff[blockIdx.x];
        rowst[i + 1] = rs1;
        cursor[i] = rs1 - deg[i];
        if (i == 0) rowst[0] = 0;
    }
}

__global__ __launch_bounds__(256) void k_scatter(const int* __restrict__ ei, int* __restrict__ cursor,
                                                 int* __restrict__ elist) {
    int e = blockIdx.x * 256 + threadIdx.x;
    if (e < NEDGES) {
        int d = ei[NEDGES + e];
        int pos = atomicAdd(&cursor[d], 1);
        elist[pos] = e;
    }
}

// ---------------- GEMMs (fp32, register-tiled) ----------------

// h1[N,256] = X[N,128] @ W[128,256]
__global__ __launch_bounds__(256) void k_gemm1(const float* __restrict__ X, const float* __restrict__ W,
                                               float* __restrict__ H) {
    __shared__ float As[64][132];   // [row][k], full K=128, pad
    __shared__ float Bs[64][68];    // [k][c] chunk of 64 k-rows, 64 cols
    int t = threadIdx.x;
    int bm = blockIdx.x * 64, bn = blockIdx.y * 64;
#pragma unroll
    for (int i = 0; i < 8; ++i) {
        int idx = i * 256 + t;
        int row = idx >> 5, k4 = (idx & 31) << 2;
        int gr = bm + row;
        float4 v = make_float4(0.f, 0.f, 0.f, 0.f);
        if (gr < NNODES) v = *(const float4*)(X + (size_t)gr * 128 + k4);
        *(float4*)&As[row][k4] = v;
    }
    int tx = t & 15, ty = t >> 4;
    float acc[4][4] = {};
    for (int kc = 0; kc < 128; kc += 64) {
#pragma unroll
        for (int i = 0; i < 4; ++i) {
            int idx = i * 256 + t;
            int row = idx >> 4, c4 = (idx & 15) << 2;
            *(float4*)&Bs[row][c4] = *(const float4*)(W + (size_t)(kc + row) * 256 + bn + c4);
        }
        __syncthreads();
        for (int k4 = 0; k4 < 64; k4 += 4) {
            float4 a[4];
#pragma unroll
            for (int i = 0; i < 4; ++i) a[i] = *(const float4*)&As[ty * 4 + i][kc + k4];
#pragma unroll
            for (int kk = 0; kk < 4; ++kk) {
                float4 b = *(const float4*)&Bs[k4 + kk][tx * 4];
#pragma unroll
                for (int i = 0; i < 4; ++i) {
                    float av = ((const float*)&a[i])[kk];
                    acc[i][0] += av * b.x; acc[i][1] += av * b.y;
                    acc[i][2] += av * b.z; acc[i][3] += av * b.w;
                }
            }
        }
        __syncthreads();
    }
#pragma unroll
    for (int i = 0; i < 4; ++i) {
        int gr = bm + ty * 4 + i;
        if (gr < NNODES)
            *(float4*)(H + (size_t)gr * 256 + bn + tx * 4) =
                make_float4(acc[i][0], acc[i][1], acc[i][2], acc[i][3]);
    }
}

// G[N,32] = H2[N,256] @ W2[256,32]
__global__ __launch_bounds__(256) void k_gemm2(const float* __restrict__ H2, const float* __restrict__ W2,
                                               float* __restrict__ G) {
    __shared__ float As[64][68];  // [row][k] chunk
    __shared__ float Bs[64][36];  // [k][c]
    int t = threadIdx.x;
    int bm = blockIdx.x * 64;
    int c = t & 31, ty = t >> 5;
    float acc[8] = {};
    for (int kc = 0; kc < 256; kc += 64) {
#pragma unroll
        for (int i = 0; i < 4; ++i) {
            int idx = i * 256 + t;
            int row = idx >> 4, k4 = (idx & 15) << 2;
            int gr = bm + row;
            float4 v = make_float4(0.f, 0.f, 0.f, 0.f);
            if (gr < NNODES) v = *(const float4*)(H2 + (size_t)gr * 256 + kc + k4);
            *(float4*)&As[row][k4] = v;
        }
#pragma unroll
        for (int i = 0; i < 2; ++i) {
            int idx = i * 256 + t;
            int row = idx >> 3, c4 = (idx & 7) << 2;
            *(float4*)&Bs[row][c4] = *(const float4*)(W2 + (size_t)(kc + row) * 32 + c4);
        }
        __syncthreads();
        for (int k = 0; k < 64; ++k) {
            float b = Bs[k][c];
#pragma unroll
            for (int r = 0; r < 8; ++r) acc[r] += As[ty * 8 + r][k] * b;
        }
        __syncthreads();
    }
#pragma unroll
    for (int r = 0; r < 8; ++r) {
        int gr = bm + ty * 8 + r;
        if (gr < NNODES) G[(size_t)gr * 32 + c] = acc[r];
    }
}

// ---------------- attention logits ----------------

// per-node: asrc1[n,h] = sum_f h1[n,h,f]*Asrc[h,f] (and adst)
__global__ __launch_bounds__(256) void k_alpha1(const float* __restrict__ h1, const float* __restrict__ Asrc,
                                                const float* __restrict__ Adst, float* __restrict__ as,
                                                float* __restrict__ ad) {
    int n = blockIdx.x, t = threadIdx.x;
    float v = h1[(size_t)n * 256 + t];
    float ps = v * Asrc[t], pd = v * Adst[t];
#pragma unroll
    for (int d = 16; d >= 1; d >>= 1) { ps += __shfl_xor(ps, d, 32); pd += __shfl_xor(pd, d, 32); }
    if ((t & 31) == 0) { as[n * 8 + (t >> 5)] = ps; ad[n * 8 + (t >> 5)] = pd; }
}

__global__ __launch_bounds__(256) void k_alpha2(const float* __restrict__ g, const float* __restrict__ Asrc,
                                                const float* __restrict__ Adst, float* __restrict__ as,
                                                float* __restrict__ ad) {
    int t = threadIdx.x;
    int n = blockIdx.x * 8 + (t >> 5), c = t & 31;
    if (n >= NNODES) return;
    float v = g[(size_t)n * 32 + c];
    float ps = v * Asrc[c], pd = v * Adst[c];
#pragma unroll
    for (int d = 16; d >= 1; d >>= 1) { ps += __shfl_xor(ps, d, 32); pd += __shfl_xor(pd, d, 32); }
    if (c == 0) { as[n] = ps; ad[n] = pd; }
}

// per-edge leakyrelu(asrc[src]+adst[dst]) for 8 heads
__global__ __launch_bounds__(256) void k_e1(const int* __restrict__ ei, const float* __restrict__ as,
                                            const float* __restrict__ ad, float* __restrict__ el) {
    int e = blockIdx.x * 256 + threadIdx.x;
    if (e >= NEDGES) return;
    int s = ei[e], d = ei[NEDGES + e];
    float4 s0 = *(const float4*)(as + (size_t)s * 8);
    float4 s1 = *(const float4*)(as + (size_t)s * 8 + 4);
    float4 d0 = *(const float4*)(ad + (size_t)d * 8);
    float4 d1 = *(const float4*)(ad + (size_t)d * 8 + 4);
    float v[8] = {s0.x + d0.x, s0.y + d0.y, s0.z + d0.z, s0.w + d0.w,
                  s1.x + d1.x, s1.y + d1.y, s1.z + d1.z, s1.w + d1.w};
#pragma unroll
    for (int h = 0; h < 8; ++h) { float x = v[h]; v[h] = x > 0.f ? x : 0.2f * x; }
    *(float4*)(el + (size_t)e * 8) = make_float4(v[0], v[1], v[2], v[3]);
    *(float4*)(el + (size_t)e * 8 + 4) = make_float4(v[4], v[5], v[6], v[7]);
}

__global__ __launch_bounds__(256) void k_e2(const int* __restrict__ ei, const float* __restrict__ as,
                                            const float* __restrict__ ad, float* __restrict__ el) {
    int e = blockIdx.x * 256 + threadIdx.x;
    if (e >= NEDGES) return;
    float x = as[ei[e]] + ad[ei[NEDGES + e]];
    el[e] = x > 0.f ? x : 0.2f * x;
}

// ---------------- segment softmax stats ----------------

// one wave per node; lane L: head = L&7, slot = L>>3
__global__ __launch_bounds__(64) void k_stats1(const int* __restrict__ rowst, const int* __restrict__ elist,
                                               const float* __restrict__ el, float* __restrict__ m1,
                                               float* __restrict__ invd1) {
    int n = blockIdx.x, L = threadIdx.x;
    int head = L & 7, slot = L >> 3;
    int s = rowst[n], e = rowst[n + 1];
    float m = -INFINITY;
    for (int j = s + slot; j < e; j += 8) m = fmaxf(m, el[(size_t)elist[j] * 8 + head]);
    m = fmaxf(m, __shfl_xor(m, 8));
    m = fmaxf(m, __shfl_xor(m, 16));
    m = fmaxf(m, __shfl_xor(m, 32));
    float sum = 0.f;
    for (int j = s + slot; j < e; j += 8) sum += __expf(el[(size_t)elist[j] * 8 + head] - m);
    sum += __shfl_xor(sum, 8);
    sum += __shfl_xor(sum, 16);
    sum += __shfl_xor(sum, 32);
    if (L < 8) { m1[n * 8 + L] = m; invd1[n * 8 + L] = 1.f / (sum + 1e-16f); }
}

__global__ __launch_bounds__(64) void k_stats2(const int* __restrict__ rowst, const int* __restrict__ elist,
                                               const float* __restrict__ el, float* __restrict__ m2,
                                               float* __restrict__ invd2) {
    int n = blockIdx.x, L = threadIdx.x;
    int s = rowst[n], e = rowst[n + 1];
    float m = -INFINITY;
    for (int j = s + L; j < e; j += 64) m = fmaxf(m, el[elist[j]]);
#pragma unroll
    for (int d = 1; d < 64; d <<= 1) m = fmaxf(m, __shfl_xor(m, d));
    float sum = 0.f;
    for (int j = s + L; j < e; j += 64) sum += __expf(el[elist[j]] - m);
#pragma unroll
    for (int d = 1; d < 64; d <<= 1) sum += __shfl_xor(sum, d);
    if (L == 0) { m2[n] = m; invd2[n] = 1.f / (sum + 1e-16f); }
}

// edge-parallel normalized weights (in-place on el)
__global__ __launch_bounds__(256) void k_aw1(const int* __restrict__ ei, const float* __restrict__ m1,
                                             const float* __restrict__ invd1, float* __restrict__ el) {
    int tid = blockIdx.x * 256 + threadIdx.x;  // over E*8
    if (tid >= NEDGES * 8) return;
    int e = tid >> 3, h = tid & 7;
    int d = ei[NEDGES + e];
    el[tid] = __expf(el[tid] - m1[d * 8 + h]) * invd1[d * 8 + h];
}

__global__ __launch_bounds__(256) void k_aw2(const int* __restrict__ ei, const float* __restrict__ m2,
                                             const float* __restrict__ invd2, float* __restrict__ el) {
    int e = blockIdx.x * 256 + threadIdx.x;
    if (e >= NEDGES) return;
    int d = ei[NEDGES + e];
    el[e] = __expf(el[e] - m2[d]) * invd2[d];
}

// ---------------- aggregation ----------------

// one 256-thread block per node; thread t = head(t>>5)*32 + f(t&31)
__global__ __launch_bounds__(256) void k_agg1(const int* __restrict__ rowst, const int* __restrict__ elist,
                                              const int* __restrict__ ei, const float* __restrict__ alpha,
                                              const float* __restrict__ h1, const float* __restrict__ b1,
                                              float* __restrict__ h2) {
    int n = blockIdx.x, t = threadIdx.x, h = t >> 5;
    int s = rowst[n], e = rowst[n + 1];
    float acc = 0.f;
    for (int j = s; j < e; ++j) {
        int eid = elist[j];
        int sn = ei[eid];
        acc += alpha[(size_t)eid * 8 + h] * h1[(size_t)sn * 256 + t];
    }
    float v = acc + b1[t];
    h2[(size_t)n * 256 + t] = v > 0.f ? v : __expf(v) - 1.f;  // ELU fused
}

// 8 nodes per 256-thread block, 32 channels each
__global__ __launch_bounds__(256) void k_agg2(const int* __restrict__ rowst, const int* __restrict__ elist,
                                              const int* __restrict__ ei, const float* __restrict__ alpha,
                                              const float* __restrict__ g, const float* __restrict__ b2,
                                              float* __restrict__ out) {
    int t = threadIdx.x;
    int n = blockIdx.x * 8 + (t >> 5), c = t & 31;
    if (n >= NNODES) return;
    int s = rowst[n], e = rowst[n + 1];
    float acc = 0.f;
    for (int j = s; j < e; ++j) {
        int eid = elist[j];
        acc += alpha[eid] * g[(size_t)ei[eid] * 32 + c];
    }
    out[(size_t)n * 32 + c] = acc + b2[c];
}

// ---------------- launch ----------------

extern "C" void kernel_launch(void* const* d_in, const int* in_sizes, int n_in,
                              void* d_out, int out_size, void* d_ws, size_t ws_size,
                              hipStream_t stream) {
    const float* x    = (const float*)d_in[0];
    const int*   ei   = (const int*)d_in[1];
    const float* W1   = (const float*)d_in[2];
    const float* As1  = (const float*)d_in[3];
    const float* Ad1  = (const float*)d_in[4];
    const float* b1   = (const float*)d_in[5];
    const float* W2   = (const float*)d_in[6];
    const float* As2  = (const float*)d_in[7];
    const float* Ad2  = (const float*)d_in[8];
    const float* b2   = (const float*)d_in[9];
    float* out = (float*)d_out;

    char* p = (char*)d_ws;
    auto alloc = [&](size_t bytes) -> char* {
        char* r = p;
        p += (bytes + 255) & ~(size_t)255;
        return r;
    };
    float* h1    = (float*)alloc((size_t)NNODES * 256 * 4);
    float* h2    = (float*)alloc((size_t)NNODES * 256 * 4);
    float* g2    = (float*)alloc((size_t)NNODES * 32 * 4);
    float* asrc1 = (float*)alloc((size_t)NNODES * 8 * 4);
    float* adst1 = (float*)alloc((size_t)NNODES * 8 * 4);
    float* m1    = (float*)alloc((size_t)NNODES * 8 * 4);
    float* invd1 = (float*)alloc((size_t)NNODES * 8 * 4);
    float* asrc2 = (float*)alloc((size_t)NNODES * 4);
    float* adst2 = (float*)alloc((size_t)NNODES * 4);
    float* m2    = (float*)alloc((size_t)NNODES * 4);
    float* invd2 = (float*)alloc((size_t)NNODES * 4);
    float* el1   = (float*)alloc((size_t)NEDGES * 8 * 4);  // -> alpha1 in place
    float* el2   = (float*)alloc((size_t)NEDGES * 4);      // -> alpha2 in place
    int* deg     = (int*)alloc((size_t)NNODES * 4);
    int* incl    = (int*)alloc((size_t)NNODES * 4);
    int* rowst   = (int*)alloc((size_t)(NNODES + 1) * 4);
    int* cursor  = (int*)alloc((size_t)NNODES * 4);
    int* elist   = (int*)alloc((size_t)NEDGES * 4);
    int* partial = (int*)alloc(256 * 4);
    int* choff   = (int*)alloc(256 * 4);

    const int EB = NEDGES / 256;        // 3125
    const int NCH = (NNODES + 255) / 256;  // 196

    hipMemsetAsync(deg, 0, (size_t)NNODES * 4, stream);
    k_deg<<<EB, 256, 0, stream>>>(ei, deg);
    k_scanA<<<NCH, 256, 0, stream>>>(deg, incl, partial);
    k_scanB<<<1, 256, 0, stream>>>(partial, choff, NCH);
    k_scanC<<<NCH, 256, 0, stream>>>(deg, incl, choff, rowst, cursor);
    k_scatter<<<EB, 256, 0, stream>>>(ei, cursor, elist);

    k_gemm1<<<dim3((NNODES + 63) / 64, 4), 256, 0, stream>>>(x, W1, h1);
    k_alpha1<<<NNODES, 256, 0, stream>>>(h1, As1, Ad1, asrc1, adst1);
    k_e1<<<EB, 256, 0, stream>>>(ei, asrc1, adst1, el1);
    k_stats1<<<NNODES, 64, 0, stream>>>(rowst, elist, el1, m1, invd1);
    k_aw1<<<(NEDGES * 8) / 256, 256, 0, stream>>>(ei, m1, invd1, el1);
    k_agg1<<<NNODES, 256, 0, stream>>>(rowst, elist, ei, el1, h1, b1, h2);

    k_gemm2<<<(NNODES + 63) / 64, 256, 0, stream>>>(h2, W2, g2);
    k_alpha2<<<(NNODES + 7) / 8, 256, 0, stream>>>(g2, As2, Ad2, asrc2, adst2);
    k_e2<<<EB, 256, 0, stream>>>(ei, asrc2, adst2, el2);
    k_stats2<<<NNODES, 64, 0, stream>>>(rowst, elist, el2, m2, invd2);
    k_aw2<<<EB, 256, 0, stream>>>(ei, m2, invd2, el2);
    k_agg2<<<(NNODES + 7) / 8, 256, 0, stream>>>(rowst, elist, ei, el2, g2, b2, out);
}

// Round 2
// 462.875 us; speedup vs baseline: 1.5804x; 1.5804x over previous
//
#include <hip/hip_runtime.h>
#include <math.h>

#define NNODES 50000
#define NEDGES 800000

// ---------------- CSR build ----------------

__global__ __launch_bounds__(256) void k_deg(const int* __restrict__ ei, int* __restrict__ deg) {
    int e = blockIdx.x * 256 + threadIdx.x;
    if (e < NEDGES) atomicAdd(&deg[ei[NEDGES + e]], 1);
}

__global__ __launch_bounds__(256) void k_scanA(const int* __restrict__ deg, int* __restrict__ incl,
                                               int* __restrict__ partial) {
    int t = threadIdx.x;
    int i = blockIdx.x * 256 + t;
    int v = (i < NNODES) ? deg[i] : 0;
    int lane = t & 63, wid = t >> 6;
    int s = v;
#pragma unroll
    for (int d = 1; d < 64; d <<= 1) { int u = __shfl_up(s, d, 64); if (lane >= d) s += u; }
    __shared__ int wtot[4];
    if (lane == 63) wtot[wid] = s;
    __syncthreads();
    int off = 0;
    for (int w = 0; w < wid; ++w) off += wtot[w];
    s += off;
    if (i < NNODES) incl[i] = s;
    if (t == 255) partial[blockIdx.x] = s;
}

__global__ __launch_bounds__(256) void k_scanB(const int* __restrict__ partial, int* __restrict__ chunkoff,
                                               int nch) {
    int t = threadIdx.x;
    int v = (t < nch) ? partial[t] : 0;
    int lane = t & 63, wid = t >> 6;
    int s = v;
#pragma unroll
    for (int d = 1; d < 64; d <<= 1) { int u = __shfl_up(s, d, 64); if (lane >= d) s += u; }
    __shared__ int wtot[4];
    if (lane == 63) wtot[wid] = s;
    __syncthreads();
    int off = 0;
    for (int w = 0; w < wid; ++w) off += wtot[w];
    s += off;
    if (t < nch) chunkoff[t] = s - v;  // exclusive
}

__global__ __launch_bounds__(256) void k_scanC(const int* __restrict__ deg, const int* __restrict__ incl,
                                               const int* __restrict__ chunkoff, int* __restrict__ rowst,
                                               int* __restrict__ cursor) {
    int i = blockIdx.x * 256 + threadIdx.x;
    if (i < NNODES) {
        int rs1 = incl[i] + chunkoff[blockIdx.x];
        rowst[i + 1] = rs1;
        cursor[i] = rs1 - deg[i];
        if (i == 0) rowst[0] = 0;
    }
}

// writes src node id and row id directly in CSR position order
__global__ __launch_bounds__(256) void k_scatter(const int* __restrict__ ei, int* __restrict__ cursor,
                                                 int* __restrict__ src_csr, int* __restrict__ rowid) {
    int e = blockIdx.x * 256 + threadIdx.x;
    if (e < NEDGES) {
        int d = ei[NEDGES + e];
        int pos = atomicAdd(&cursor[d], 1);
        src_csr[pos] = ei[e];
        rowid[pos] = d;
    }
}

// ---------------- GEMMs (fp32, register-tiled) ----------------

// h1[N,256] = X[N,128] @ W[128,256]
__global__ __launch_bounds__(256) void k_gemm1(const float* __restrict__ X, const float* __restrict__ W,
                                               float* __restrict__ H) {
    __shared__ float As[64][132];
    __shared__ float Bs[64][68];
    int t = threadIdx.x;
    int bm = blockIdx.x * 64, bn = blockIdx.y * 64;
#pragma unroll
    for (int i = 0; i < 8; ++i) {
        int idx = i * 256 + t;
        int row = idx >> 5, k4 = (idx & 31) << 2;
        int gr = bm + row;
        float4 v = make_float4(0.f, 0.f, 0.f, 0.f);
        if (gr < NNODES) v = *(const float4*)(X + (size_t)gr * 128 + k4);
        *(float4*)&As[row][k4] = v;
    }
    int tx = t & 15, ty = t >> 4;
    float acc[4][4] = {};
    for (int kc = 0; kc < 128; kc += 64) {
#pragma unroll
        for (int i = 0; i < 4; ++i) {
            int idx = i * 256 + t;
            int row = idx >> 4, c4 = (idx & 15) << 2;
            *(float4*)&Bs[row][c4] = *(const float4*)(W + (size_t)(kc + row) * 256 + bn + c4);
        }
        __syncthreads();
        for (int k4 = 0; k4 < 64; k4 += 4) {
            float4 a[4];
#pragma unroll
            for (int i = 0; i < 4; ++i) a[i] = *(const float4*)&As[ty * 4 + i][kc + k4];
#pragma unroll
            for (int kk = 0; kk < 4; ++kk) {
                float4 b = *(const float4*)&Bs[k4 + kk][tx * 4];
#pragma unroll
                for (int i = 0; i < 4; ++i) {
                    float av = ((const float*)&a[i])[kk];
                    acc[i][0] += av * b.x; acc[i][1] += av * b.y;
                    acc[i][2] += av * b.z; acc[i][3] += av * b.w;
                }
            }
        }
        __syncthreads();
    }
#pragma unroll
    for (int i = 0; i < 4; ++i) {
        int gr = bm + ty * 4 + i;
        if (gr < NNODES)
            *(float4*)(H + (size_t)gr * 256 + bn + tx * 4) =
                make_float4(acc[i][0], acc[i][1], acc[i][2], acc[i][3]);
    }
}

// G[N,32] = H2[N,256] @ W2[256,32]
__global__ __launch_bounds__(256) void k_gemm2(const float* __restrict__ H2, const float* __restrict__ W2,
                                               float* __restrict__ G) {
    __shared__ float As[64][68];
    __shared__ float Bs[64][36];
    int t = threadIdx.x;
    int bm = blockIdx.x * 64;
    int c = t & 31, ty = t >> 5;
    float acc[8] = {};
    for (int kc = 0; kc < 256; kc += 64) {
#pragma unroll
        for (int i = 0; i < 4; ++i) {
            int idx = i * 256 + t;
            int row = idx >> 4, k4 = (idx & 15) << 2;
            int gr = bm + row;
            float4 v = make_float4(0.f, 0.f, 0.f, 0.f);
            if (gr < NNODES) v = *(const float4*)(H2 + (size_t)gr * 256 + kc + k4);
            *(float4*)&As[row][k4] = v;
        }
#pragma unroll
        for (int i = 0; i < 2; ++i) {
            int idx = i * 256 + t;
            int row = idx >> 3, c4 = (idx & 7) << 2;
            *(float4*)&Bs[row][c4] = *(const float4*)(W2 + (size_t)(kc + row) * 32 + c4);
        }
        __syncthreads();
        for (int k = 0; k < 64; ++k) {
            float b = Bs[k][c];
#pragma unroll
            for (int r = 0; r < 8; ++r) acc[r] += As[ty * 8 + r][k] * b;
        }
        __syncthreads();
    }
#pragma unroll
    for (int r = 0; r < 8; ++r) {
        int gr = bm + ty * 8 + r;
        if (gr < NNODES) G[(size_t)gr * 32 + c] = acc[r];
    }
}

// ---------------- attention logits ----------------

__global__ __launch_bounds__(256) void k_alpha1(const float* __restrict__ h1, const float* __restrict__ Asrc,
                                                const float* __restrict__ Adst, float* __restrict__ as,
                                                float* __restrict__ ad) {
    int n = blockIdx.x, t = threadIdx.x;
    float v = h1[(size_t)n * 256 + t];
    float ps = v * Asrc[t], pd = v * Adst[t];
#pragma unroll
    for (int d = 16; d >= 1; d >>= 1) { ps += __shfl_xor(ps, d, 32); pd += __shfl_xor(pd, d, 32); }
    if ((t & 31) == 0) { as[n * 8 + (t >> 5)] = ps; ad[n * 8 + (t >> 5)] = pd; }
}

__global__ __launch_bounds__(256) void k_alpha2(const float* __restrict__ g, const float* __restrict__ Asrc,
                                                const float* __restrict__ Adst, float* __restrict__ as,
                                                float* __restrict__ ad) {
    int t = threadIdx.x;
    int n = blockIdx.x * 8 + (t >> 5), c = t & 31;
    if (n >= NNODES) return;
    float v = g[(size_t)n * 32 + c];
    float ps = v * Asrc[c], pd = v * Adst[c];
#pragma unroll
    for (int d = 16; d >= 1; d >>= 1) { ps += __shfl_xor(ps, d, 32); pd += __shfl_xor(pd, d, 32); }
    if (c == 0) { as[n] = ps; ad[n] = pd; }
}

// position-parallel over CSR slots: coalesced writes of logits in CSR order
__global__ __launch_bounds__(256) void k_e1(const int* __restrict__ src_csr, const int* __restrict__ rowid,
                                            const float* __restrict__ as, const float* __restrict__ ad,
                                            float* __restrict__ el) {
    int p = blockIdx.x * 256 + threadIdx.x;
    if (p >= NEDGES) return;
    int s = src_csr[p], d = rowid[p];
    float4 s0 = *(const float4*)(as + (size_t)s * 8);
    float4 s1 = *(const float4*)(as + (size_t)s * 8 + 4);
    float4 d0 = *(const float4*)(ad + (size_t)d * 8);
    float4 d1 = *(const float4*)(ad + (size_t)d * 8 + 4);
    float v[8] = {s0.x + d0.x, s0.y + d0.y, s0.z + d0.z, s0.w + d0.w,
                  s1.x + d1.x, s1.y + d1.y, s1.z + d1.z, s1.w + d1.w};
#pragma unroll
    for (int h = 0; h < 8; ++h) { float x = v[h]; v[h] = x > 0.f ? x : 0.2f * x; }
    *(float4*)(el + (size_t)p * 8) = make_float4(v[0], v[1], v[2], v[3]);
    *(float4*)(el + (size_t)p * 8 + 4) = make_float4(v[4], v[5], v[6], v[7]);
}

__global__ __launch_bounds__(256) void k_e2(const int* __restrict__ src_csr, const int* __restrict__ rowid,
                                            const float* __restrict__ as, const float* __restrict__ ad,
                                            float* __restrict__ el) {
    int p = blockIdx.x * 256 + threadIdx.x;
    if (p >= NEDGES) return;
    float x = as[src_csr[p]] + ad[rowid[p]];
    el[p] = x > 0.f ? x : 0.2f * x;
}

// ---------------- fused softmax + aggregate ----------------

// one 256-thread block per node; fused: segment softmax stats + alpha + weighted
// gather-sum + bias + ELU.  thread t -> head t>>5, channel t&31.
__global__ __launch_bounds__(256) void k_agg1(const int* __restrict__ rowst, const int* __restrict__ src_csr,
                                              const float* __restrict__ el, const float* __restrict__ h1,
                                              const float* __restrict__ b1, float* __restrict__ h2) {
    int n = blockIdx.x, t = threadIdx.x;
    __shared__ float sm[8], sinv[8];
    __shared__ float salpha[512];
    __shared__ int ssrc[64];
    __shared__ int sse[2];
    if (t < 2) sse[t] = rowst[n + t];
    __syncthreads();
    int s = sse[0], e = sse[1];
    // phase 1: per-head max + denom (wave 0 only; el reads are contiguous)
    if (t < 64) {
        int head = t & 7, slot = t >> 3;
        float m = -INFINITY;
        for (int j = s + slot; j < e; j += 8) m = fmaxf(m, el[(size_t)j * 8 + head]);
        m = fmaxf(m, __shfl_xor(m, 8));
        m = fmaxf(m, __shfl_xor(m, 16));
        m = fmaxf(m, __shfl_xor(m, 32));
        float sum = 0.f;
        for (int j = s + slot; j < e; j += 8) sum += __expf(el[(size_t)j * 8 + head] - m);
        sum += __shfl_xor(sum, 8);
        sum += __shfl_xor(sum, 16);
        sum += __shfl_xor(sum, 32);
        if (t < 8) { sm[t] = m; sinv[t] = 1.f / (sum + 1e-16f); }
    }
    __syncthreads();
    int head = t >> 5;
    float acc = 0.f;
    for (int jc = s; jc < e; jc += 64) {
        int cl = min(64, e - jc);
        // stage alpha + src in LDS (each alpha computed once)
        for (int idx = t; idx < cl * 8; idx += 256) {
            int jj = idx >> 3, h = idx & 7;
            salpha[idx] = __expf(el[(size_t)(jc + jj) * 8 + h] - sm[h]) * sinv[h];
        }
        if (t < cl) ssrc[t] = src_csr[jc + t];
        __syncthreads();
        int jj = 0;
        for (; jj + 8 <= cl; jj += 8) {
            int i0 = ssrc[jj], i1 = ssrc[jj + 1], i2 = ssrc[jj + 2], i3 = ssrc[jj + 3];
            int i4 = ssrc[jj + 4], i5 = ssrc[jj + 5], i6 = ssrc[jj + 6], i7 = ssrc[jj + 7];
            float a0 = salpha[jj * 8 + head],       a1 = salpha[(jj + 1) * 8 + head];
            float a2 = salpha[(jj + 2) * 8 + head], a3 = salpha[(jj + 3) * 8 + head];
            float a4 = salpha[(jj + 4) * 8 + head], a5 = salpha[(jj + 5) * 8 + head];
            float a6 = salpha[(jj + 6) * 8 + head], a7 = salpha[(jj + 7) * 8 + head];
            float v0 = h1[(size_t)i0 * 256 + t], v1 = h1[(size_t)i1 * 256 + t];
            float v2 = h1[(size_t)i2 * 256 + t], v3 = h1[(size_t)i3 * 256 + t];
            float v4 = h1[(size_t)i4 * 256 + t], v5 = h1[(size_t)i5 * 256 + t];
            float v6 = h1[(size_t)i6 * 256 + t], v7 = h1[(size_t)i7 * 256 + t];
            acc += a0 * v0 + a1 * v1 + a2 * v2 + a3 * v3 + a4 * v4 + a5 * v5 + a6 * v6 + a7 * v7;
        }
        for (; jj + 4 <= cl; jj += 4) {
            int i0 = ssrc[jj], i1 = ssrc[jj + 1], i2 = ssrc[jj + 2], i3 = ssrc[jj + 3];
            float a0 = salpha[jj * 8 + head],       a1 = salpha[(jj + 1) * 8 + head];
            float a2 = salpha[(jj + 2) * 8 + head], a3 = salpha[(jj + 3) * 8 + head];
            float v0 = h1[(size_t)i0 * 256 + t], v1 = h1[(size_t)i1 * 256 + t];
            float v2 = h1[(size_t)i2 * 256 + t], v3 = h1[(size_t)i3 * 256 + t];
            acc += a0 * v0 + a1 * v1 + a2 * v2 + a3 * v3;
        }
        for (; jj < cl; ++jj)
            acc += salpha[jj * 8 + head] * h1[(size_t)ssrc[jj] * 256 + t];
        __syncthreads();
    }
    float v = acc + b1[t];
    h2[(size_t)n * 256 + t] = v > 0.f ? v : __expf(v) - 1.f;  // fused ELU
}

// 8 nodes per block, 32 channels each; fused softmax + aggregate + bias
__global__ __launch_bounds__(256) void k_agg2(const int* __restrict__ rowst, const int* __restrict__ src_csr,
                                              const float* __restrict__ el, const float* __restrict__ g,
                                              const float* __restrict__ b2, float* __restrict__ out) {
    int t = threadIdx.x;
    int n = blockIdx.x * 8 + (t >> 5), c = t & 31;
    if (n >= NNODES) return;
    int s = rowst[n], e = rowst[n + 1];
    float m = -INFINITY;
    for (int j = s + c; j < e; j += 32) m = fmaxf(m, el[j]);
#pragma unroll
    for (int d = 16; d >= 1; d >>= 1) m = fmaxf(m, __shfl_xor(m, d, 32));
    float sum = 0.f;
    for (int j = s + c; j < e; j += 32) sum += __expf(el[j] - m);
#pragma unroll
    for (int d = 16; d >= 1; d >>= 1) sum += __shfl_xor(sum, d, 32);
    float inv = 1.f / (sum + 1e-16f);
    float acc = 0.f;
    int j = s;
    for (; j + 4 <= e; j += 4) {
        int i0 = src_csr[j], i1 = src_csr[j + 1], i2 = src_csr[j + 2], i3 = src_csr[j + 3];
        float a0 = __expf(el[j] - m) * inv,     a1 = __expf(el[j + 1] - m) * inv;
        float a2 = __expf(el[j + 2] - m) * inv, a3 = __expf(el[j + 3] - m) * inv;
        acc += a0 * g[(size_t)i0 * 32 + c] + a1 * g[(size_t)i1 * 32 + c]
             + a2 * g[(size_t)i2 * 32 + c] + a3 * g[(size_t)i3 * 32 + c];
    }
    for (; j < e; ++j) acc += __expf(el[j] - m) * inv * g[(size_t)src_csr[j] * 32 + c];
    out[(size_t)n * 32 + c] = acc + b2[c];
}

// ---------------- launch ----------------

extern "C" void kernel_launch(void* const* d_in, const int* in_sizes, int n_in,
                              void* d_out, int out_size, void* d_ws, size_t ws_size,
                              hipStream_t stream) {
    const float* x    = (const float*)d_in[0];
    const int*   ei   = (const int*)d_in[1];
    const float* W1   = (const float*)d_in[2];
    const float* As1  = (const float*)d_in[3];
    const float* Ad1  = (const float*)d_in[4];
    const float* b1   = (const float*)d_in[5];
    const float* W2   = (const float*)d_in[6];
    const float* As2  = (const float*)d_in[7];
    const float* Ad2  = (const float*)d_in[8];
    const float* b2   = (const float*)d_in[9];
    float* out = (float*)d_out;

    char* p = (char*)d_ws;
    auto alloc = [&](size_t bytes) -> char* {
        char* r = p;
        p += (bytes + 255) & ~(size_t)255;
        return r;
    };
    float* h1    = (float*)alloc((size_t)NNODES * 256 * 4);
    float* h2    = (float*)alloc((size_t)NNODES * 256 * 4);
    float* g2    = (float*)alloc((size_t)NNODES * 32 * 4);
    float* asrc1 = (float*)alloc((size_t)NNODES * 8 * 4);
    float* adst1 = (float*)alloc((size_t)NNODES * 8 * 4);
    float* asrc2 = (float*)alloc((size_t)NNODES * 4);
    float* adst2 = (float*)alloc((size_t)NNODES * 4);
    float* el1   = (float*)alloc((size_t)NEDGES * 8 * 4);
    float* el2   = (float*)alloc((size_t)NEDGES * 4);
    int* deg     = (int*)alloc((size_t)NNODES * 4);
    int* incl    = (int*)alloc((size_t)NNODES * 4);
    int* rowst   = (int*)alloc((size_t)(NNODES + 1) * 4);
    int* cursor  = (int*)alloc((size_t)NNODES * 4);
    int* src_csr = (int*)alloc((size_t)NEDGES * 4);
    int* rowid   = (int*)alloc((size_t)NEDGES * 4);
    int* partial = (int*)alloc(256 * 4);
    int* choff   = (int*)alloc(256 * 4);

    const int EB = NEDGES / 256;           // 3125
    const int NCH = (NNODES + 255) / 256;  // 196

    hipMemsetAsync(deg, 0, (size_t)NNODES * 4, stream);
    k_deg<<<EB, 256, 0, stream>>>(ei, deg);
    k_scanA<<<NCH, 256, 0, stream>>>(deg, incl, partial);
    k_scanB<<<1, 256, 0, stream>>>(partial, choff, NCH);
    k_scanC<<<NCH, 256, 0, stream>>>(deg, incl, choff, rowst, cursor);
    k_scatter<<<EB, 256, 0, stream>>>(ei, cursor, src_csr, rowid);

    k_gemm1<<<dim3((NNODES + 63) / 64, 4), 256, 0, stream>>>(x, W1, h1);
    k_alpha1<<<NNODES, 256, 0, stream>>>(h1, As1, Ad1, asrc1, adst1);
    k_e1<<<EB, 256, 0, stream>>>(src_csr, rowid, asrc1, adst1, el1);
    k_agg1<<<NNODES, 256, 0, stream>>>(rowst, src_csr, el1, h1, b1, h2);

    k_gemm2<<<(NNODES + 63) / 64, 256, 0, stream>>>(h2, W2, g2);
    k_alpha2<<<(NNODES + 7) / 8, 256, 0, stream>>>(g2, As2, Ad2, asrc2, adst2);
    k_e2<<<EB, 256, 0, stream>>>(src_csr, rowid, asrc2, adst2, el2);
    k_agg2<<<(NNODES + 7) / 8, 256, 0, stream>>>(rowst, src_csr, el2, g2, b2, out);
}

// Round 3
// 437.797 us; speedup vs baseline: 1.6710x; 1.0573x over previous
//
#include <hip/hip_runtime.h>
#include <math.h>

#define NNODES 50000
#define NEDGES 800000

typedef _Float16 f16;
typedef _Float16 f16x8 __attribute__((ext_vector_type(8)));
typedef _Float16 f16x4 __attribute__((ext_vector_type(4)));
typedef float f32x4 __attribute__((ext_vector_type(4)));

// ---------------- CSR build ----------------

__global__ __launch_bounds__(256) void k_deg(const int* __restrict__ ei, int* __restrict__ deg) {
    int e = blockIdx.x * 256 + threadIdx.x;
    if (e < NEDGES) atomicAdd(&deg[ei[NEDGES + e]], 1);
}

__global__ __launch_bounds__(256) void k_scanA(const int* __restrict__ deg, int* __restrict__ incl,
                                               int* __restrict__ partial) {
    int t = threadIdx.x;
    int i = blockIdx.x * 256 + t;
    int v = (i < NNODES) ? deg[i] : 0;
    int lane = t & 63, wid = t >> 6;
    int s = v;
#pragma unroll
    for (int d = 1; d < 64; d <<= 1) { int u = __shfl_up(s, d, 64); if (lane >= d) s += u; }
    __shared__ int wtot[4];
    if (lane == 63) wtot[wid] = s;
    __syncthreads();
    int off = 0;
    for (int w = 0; w < wid; ++w) off += wtot[w];
    s += off;
    if (i < NNODES) incl[i] = s;
    if (t == 255) partial[blockIdx.x] = s;
}

__global__ __launch_bounds__(256) void k_scanB(const int* __restrict__ partial, int* __restrict__ chunkoff,
                                               int nch) {
    int t = threadIdx.x;
    int v = (t < nch) ? partial[t] : 0;
    int lane = t & 63, wid = t >> 6;
    int s = v;
#pragma unroll
    for (int d = 1; d < 64; d <<= 1) { int u = __shfl_up(s, d, 64); if (lane >= d) s += u; }
    __shared__ int wtot[4];
    if (lane == 63) wtot[wid] = s;
    __syncthreads();
    int off = 0;
    for (int w = 0; w < wid; ++w) off += wtot[w];
    s += off;
    if (t < nch) chunkoff[t] = s - v;  // exclusive
}

__global__ __launch_bounds__(256) void k_scanC(const int* __restrict__ deg, const int* __restrict__ incl,
                                               const int* __restrict__ chunkoff, int* __restrict__ rowst,
                                               int* __restrict__ cursor) {
    int i = blockIdx.x * 256 + threadIdx.x;
    if (i < NNODES) {
        int rs1 = incl[i] + chunkoff[blockIdx.x];
        rowst[i + 1] = rs1;
        cursor[i] = rs1 - deg[i];
        if (i == 0) rowst[0] = 0;
    }
}

__global__ __launch_bounds__(256) void k_scatter(const int* __restrict__ ei, int* __restrict__ cursor,
                                                 int* __restrict__ src_csr, int* __restrict__ rowid) {
    int e = blockIdx.x * 256 + threadIdx.x;
    if (e < NEDGES) {
        int d = ei[NEDGES + e];
        int pos = atomicAdd(&cursor[d], 1);
        src_csr[pos] = ei[e];
        rowid[pos] = d;
    }
}

// ---------------- MFMA GEMMs (fp16 in, fp32 acc) ----------------
// mfma_f32_16x16x32_f16 layouts (lane = tid&63, r = lane&15, quad = lane>>4):
//   A frag a[j] = A[row=r][k=quad*8+j]
//   B frag b[j] = B[k=quad*8+j][col=r]
//   D frag d[i] = D[row=quad*4+i][col=r]

// h1h[N,256](f16) = X[N,128](f32) @ W1[128,256](f32); block: 64 rows x 128 cols
__global__ __launch_bounds__(256) void k_gemm1(const float* __restrict__ X, const float* __restrict__ W1,
                                               f16* __restrict__ h1h) {
    __shared__ f16 sA[64 * 136];            // [row][k], stride 136
    __shared__ f16 sB[4 * 128 * 4 * 8];     // ((kc*128 + c)*4 + quad)*8 + j
    int t = threadIdx.x;
    int bm = blockIdx.x * 64, bn = blockIdx.y * 128;
    // stage A: 64x128 fp32 -> fp16 (2048 float4)
#pragma unroll
    for (int i = 0; i < 8; ++i) {
        int idx = i * 256 + t;
        int row = idx >> 5, c4 = (idx & 31) << 2;
        int gr = bm + row;
        float4 v = make_float4(0.f, 0.f, 0.f, 0.f);
        if (gr < NNODES) v = *(const float4*)(X + (size_t)gr * 128 + c4);
        f16x4 h = {(f16)v.x, (f16)v.y, (f16)v.z, (f16)v.w};
        *(f16x4*)&sA[row * 136 + c4] = h;
    }
    // stage B: 128x128 fp32 -> fp16 fragment-major (4096 float4)
#pragma unroll
    for (int i = 0; i < 16; ++i) {
        int idx = i * 256 + t;
        int k = idx >> 5, c4 = (idx & 31) << 2;
        float4 v = *(const float4*)(W1 + (size_t)k * 256 + bn + c4);
        int kc = k >> 5, quad = (k & 31) >> 3, j = k & 7;
        float vv[4] = {v.x, v.y, v.z, v.w};
#pragma unroll
        for (int cc = 0; cc < 4; ++cc)
            sB[(((kc << 7) + c4 + cc) * 4 + quad) * 8 + j] = (f16)vv[cc];
    }
    __syncthreads();
    int lane = t & 63, w = t >> 6;
    int r = lane & 15, quad = lane >> 4;
    int r0 = w * 16;
    f32x4 acc[8];
#pragma unroll
    for (int nt = 0; nt < 8; ++nt) acc[nt] = (f32x4){0.f, 0.f, 0.f, 0.f};
#pragma unroll
    for (int kc = 0; kc < 4; ++kc) {
        f16x8 a = *(f16x8*)&sA[(r0 + r) * 136 + kc * 32 + quad * 8];
#pragma unroll
        for (int nt = 0; nt < 8; ++nt) {
            f16x8 b = *(f16x8*)&sB[(((kc << 7) + nt * 16 + r) * 4 + quad) * 8];
            acc[nt] = __builtin_amdgcn_mfma_f32_16x16x32_f16(a, b, acc[nt], 0, 0, 0);
        }
    }
#pragma unroll
    for (int nt = 0; nt < 8; ++nt)
#pragma unroll
        for (int i = 0; i < 4; ++i) {
            int gr = bm + r0 + quad * 4 + i;
            if (gr < NNODES) h1h[(size_t)gr * 256 + bn + nt * 16 + r] = (f16)acc[nt][i];
        }
}

// g[N,32](f32) = h2h[N,256](f16) @ W2[256,32](f32); block: 64 rows
__global__ __launch_bounds__(256) void k_gemm2(const f16* __restrict__ h2h, const float* __restrict__ W2,
                                               float* __restrict__ g) {
    __shared__ f16 sA[64 * 264];            // [row][k], stride 264
    __shared__ f16 sB[8 * 32 * 4 * 8];      // ((kc*32 + c)*4 + quad)*8 + j
    int t = threadIdx.x;
    int bm = blockIdx.x * 64;
    // stage A: 64x256 f16 copy (2048 x 16B)
#pragma unroll
    for (int i = 0; i < 8; ++i) {
        int idx = i * 256 + t;
        int row = idx >> 5, k8 = (idx & 31) << 3;
        int gr = bm + row;
        f16x8 v = {};
        if (gr < NNODES) v = *(const f16x8*)(h2h + (size_t)gr * 256 + k8);
        *(f16x8*)&sA[row * 264 + k8] = v;
    }
    // stage B: 256x32 fp32 -> fp16 fragment-major (2048 float4)
#pragma unroll
    for (int i = 0; i < 8; ++i) {
        int idx = i * 256 + t;
        int k = idx >> 3, c4 = (idx & 7) << 2;
        float4 v = *(const float4*)(W2 + (size_t)k * 32 + c4);
        int kc = k >> 5, quad = (k & 31) >> 3, j = k & 7;
        float vv[4] = {v.x, v.y, v.z, v.w};
#pragma unroll
        for (int cc = 0; cc < 4; ++cc)
            sB[(((kc << 5) + c4 + cc) * 4 + quad) * 8 + j] = (f16)vv[cc];
    }
    __syncthreads();
    int lane = t & 63, w = t >> 6;
    int r = lane & 15, quad = lane >> 4;
    int r0 = w * 16;
    f32x4 acc[2];
    acc[0] = (f32x4){0.f, 0.f, 0.f, 0.f};
    acc[1] = (f32x4){0.f, 0.f, 0.f, 0.f};
#pragma unroll
    for (int kc = 0; kc < 8; ++kc) {
        f16x8 a = *(f16x8*)&sA[(r0 + r) * 264 + kc * 32 + quad * 8];
#pragma unroll
        for (int nt = 0; nt < 2; ++nt) {
            f16x8 b = *(f16x8*)&sB[(((kc << 5) + nt * 16 + r) * 4 + quad) * 8];
            acc[nt] = __builtin_amdgcn_mfma_f32_16x16x32_f16(a, b, acc[nt], 0, 0, 0);
        }
    }
#pragma unroll
    for (int nt = 0; nt < 2; ++nt)
#pragma unroll
        for (int i = 0; i < 4; ++i) {
            int gr = bm + r0 + quad * 4 + i;
            if (gr < NNODES) g[(size_t)gr * 32 + nt * 16 + r] = acc[nt][i];
        }
}

// ---------------- attention logits ----------------

__global__ __launch_bounds__(256) void k_alpha1(const f16* __restrict__ h1h, const float* __restrict__ Asrc,
                                                const float* __restrict__ Adst, float* __restrict__ as,
                                                float* __restrict__ ad) {
    int n = blockIdx.x, t = threadIdx.x;
    float v = (float)h1h[(size_t)n * 256 + t];
    float ps = v * Asrc[t], pd = v * Adst[t];
#pragma unroll
    for (int d = 16; d >= 1; d >>= 1) { ps += __shfl_xor(ps, d, 32); pd += __shfl_xor(pd, d, 32); }
    if ((t & 31) == 0) { as[n * 8 + (t >> 5)] = ps; ad[n * 8 + (t >> 5)] = pd; }
}

__global__ __launch_bounds__(256) void k_alpha2(const float* __restrict__ g, const float* __restrict__ Asrc,
                                                const float* __restrict__ Adst, float* __restrict__ as,
                                                float* __restrict__ ad) {
    int t = threadIdx.x;
    int n = blockIdx.x * 8 + (t >> 5), c = t & 31;
    if (n >= NNODES) return;
    float v = g[(size_t)n * 32 + c];
    float ps = v * Asrc[c], pd = v * Adst[c];
#pragma unroll
    for (int d = 16; d >= 1; d >>= 1) { ps += __shfl_xor(ps, d, 32); pd += __shfl_xor(pd, d, 32); }
    if (c == 0) { as[n] = ps; ad[n] = pd; }
}

__global__ __launch_bounds__(256) void k_e1(const int* __restrict__ src_csr, const int* __restrict__ rowid,
                                            const float* __restrict__ as, const float* __restrict__ ad,
                                            float* __restrict__ el) {
    int p = blockIdx.x * 256 + threadIdx.x;
    if (p >= NEDGES) return;
    int s = src_csr[p], d = rowid[p];
    float4 s0 = *(const float4*)(as + (size_t)s * 8);
    float4 s1 = *(const float4*)(as + (size_t)s * 8 + 4);
    float4 d0 = *(const float4*)(ad + (size_t)d * 8);
    float4 d1 = *(const float4*)(ad + (size_t)d * 8 + 4);
    float v[8] = {s0.x + d0.x, s0.y + d0.y, s0.z + d0.z, s0.w + d0.w,
                  s1.x + d1.x, s1.y + d1.y, s1.z + d1.z, s1.w + d1.w};
#pragma unroll
    for (int h = 0; h < 8; ++h) { float x = v[h]; v[h] = x > 0.f ? x : 0.2f * x; }
    *(float4*)(el + (size_t)p * 8) = make_float4(v[0], v[1], v[2], v[3]);
    *(float4*)(el + (size_t)p * 8 + 4) = make_float4(v[4], v[5], v[6], v[7]);
}

__global__ __launch_bounds__(256) void k_e2(const int* __restrict__ src_csr, const int* __restrict__ rowid,
                                            const float* __restrict__ as, const float* __restrict__ ad,
                                            float* __restrict__ el) {
    int p = blockIdx.x * 256 + threadIdx.x;
    if (p >= NEDGES) return;
    float x = as[src_csr[p]] + ad[rowid[p]];
    el[p] = x > 0.f ? x : 0.2f * x;
}

// ---------------- fused softmax + aggregate ----------------

// one 256-thread block per node; h1 gathered in fp16, fp32 accumulate, ELU, h2 in fp16
__global__ __launch_bounds__(256) void k_agg1(const int* __restrict__ rowst, const int* __restrict__ src_csr,
                                              const float* __restrict__ el, const f16* __restrict__ h1h,
                                              const float* __restrict__ b1, f16* __restrict__ h2h) {
    int n = blockIdx.x, t = threadIdx.x;
    __shared__ float sm[8], sinv[8];
    __shared__ float salpha[512];
    __shared__ int ssrc[64];
    __shared__ int sse[2];
    if (t < 2) sse[t] = rowst[n + t];
    __syncthreads();
    int s = sse[0], e = sse[1];
    if (t < 64) {
        int head = t & 7, slot = t >> 3;
        float m = -INFINITY;
        for (int j = s + slot; j < e; j += 8) m = fmaxf(m, el[(size_t)j * 8 + head]);
        m = fmaxf(m, __shfl_xor(m, 8));
        m = fmaxf(m, __shfl_xor(m, 16));
        m = fmaxf(m, __shfl_xor(m, 32));
        float sum = 0.f;
        for (int j = s + slot; j < e; j += 8) sum += __expf(el[(size_t)j * 8 + head] - m);
        sum += __shfl_xor(sum, 8);
        sum += __shfl_xor(sum, 16);
        sum += __shfl_xor(sum, 32);
        if (t < 8) { sm[t] = m; sinv[t] = 1.f / (sum + 1e-16f); }
    }
    __syncthreads();
    int head = t >> 5;
    float acc = 0.f;
    for (int jc = s; jc < e; jc += 64) {
        int cl = min(64, e - jc);
        for (int idx = t; idx < cl * 8; idx += 256) {
            int jj = idx >> 3, h = idx & 7;
            salpha[idx] = __expf(el[(size_t)(jc + jj) * 8 + h] - sm[h]) * sinv[h];
        }
        if (t < cl) ssrc[t] = src_csr[jc + t];
        __syncthreads();
        int jj = 0;
        for (; jj + 8 <= cl; jj += 8) {
            int i0 = ssrc[jj], i1 = ssrc[jj + 1], i2 = ssrc[jj + 2], i3 = ssrc[jj + 3];
            int i4 = ssrc[jj + 4], i5 = ssrc[jj + 5], i6 = ssrc[jj + 6], i7 = ssrc[jj + 7];
            float a0 = salpha[jj * 8 + head],       a1 = salpha[(jj + 1) * 8 + head];
            float a2 = salpha[(jj + 2) * 8 + head], a3 = salpha[(jj + 3) * 8 + head];
            float a4 = salpha[(jj + 4) * 8 + head], a5 = salpha[(jj + 5) * 8 + head];
            float a6 = salpha[(jj + 6) * 8 + head], a7 = salpha[(jj + 7) * 8 + head];
            float v0 = (float)h1h[(size_t)i0 * 256 + t], v1 = (float)h1h[(size_t)i1 * 256 + t];
            float v2 = (float)h1h[(size_t)i2 * 256 + t], v3 = (float)h1h[(size_t)i3 * 256 + t];
            float v4 = (float)h1h[(size_t)i4 * 256 + t], v5 = (float)h1h[(size_t)i5 * 256 + t];
            float v6 = (float)h1h[(size_t)i6 * 256 + t], v7 = (float)h1h[(size_t)i7 * 256 + t];
            acc += a0 * v0 + a1 * v1 + a2 * v2 + a3 * v3 + a4 * v4 + a5 * v5 + a6 * v6 + a7 * v7;
        }
        for (; jj + 4 <= cl; jj += 4) {
            int i0 = ssrc[jj], i1 = ssrc[jj + 1], i2 = ssrc[jj + 2], i3 = ssrc[jj + 3];
            float a0 = salpha[jj * 8 + head],       a1 = salpha[(jj + 1) * 8 + head];
            float a2 = salpha[(jj + 2) * 8 + head], a3 = salpha[(jj + 3) * 8 + head];
            float v0 = (float)h1h[(size_t)i0 * 256 + t], v1 = (float)h1h[(size_t)i1 * 256 + t];
            float v2 = (float)h1h[(size_t)i2 * 256 + t], v3 = (float)h1h[(size_t)i3 * 256 + t];
            acc += a0 * v0 + a1 * v1 + a2 * v2 + a3 * v3;
        }
        for (; jj < cl; ++jj)
            acc += salpha[jj * 8 + head] * (float)h1h[(size_t)ssrc[jj] * 256 + t];
        __syncthreads();
    }
    float v = acc + b1[t];
    h2h[(size_t)n * 256 + t] = (f16)(v > 0.f ? v : __expf(v) - 1.f);  // fused ELU
}

// 8 nodes per block, 32 channels each; fused softmax + aggregate + bias (g stays fp32)
__global__ __launch_bounds__(256) void k_agg2(const int* __restrict__ rowst, const int* __restrict__ src_csr,
                                              const float* __restrict__ el, const float* __restrict__ g,
                                              const float* __restrict__ b2, float* __restrict__ out) {
    int t = threadIdx.x;
    int n = blockIdx.x * 8 + (t >> 5), c = t & 31;
    if (n >= NNODES) return;
    int s = rowst[n], e = rowst[n + 1];
    float m = -INFINITY;
    for (int j = s + c; j < e; j += 32) m = fmaxf(m, el[j]);
#pragma unroll
    for (int d = 16; d >= 1; d >>= 1) m = fmaxf(m, __shfl_xor(m, d, 32));
    float sum = 0.f;
    for (int j = s + c; j < e; j += 32) sum += __expf(el[j] - m);
#pragma unroll
    for (int d = 16; d >= 1; d >>= 1) sum += __shfl_xor(sum, d, 32);
    float inv = 1.f / (sum + 1e-16f);
    float acc = 0.f;
    int j = s;
    for (; j + 4 <= e; j += 4) {
        int i0 = src_csr[j], i1 = src_csr[j + 1], i2 = src_csr[j + 2], i3 = src_csr[j + 3];
        float a0 = __expf(el[j] - m) * inv,     a1 = __expf(el[j + 1] - m) * inv;
        float a2 = __expf(el[j + 2] - m) * inv, a3 = __expf(el[j + 3] - m) * inv;
        acc += a0 * g[(size_t)i0 * 32 + c] + a1 * g[(size_t)i1 * 32 + c]
             + a2 * g[(size_t)i2 * 32 + c] + a3 * g[(size_t)i3 * 32 + c];
    }
    for (; j < e; ++j) acc += __expf(el[j] - m) * inv * g[(size_t)src_csr[j] * 32 + c];
    out[(size_t)n * 32 + c] = acc + b2[c];
}

// ---------------- launch ----------------

extern "C" void kernel_launch(void* const* d_in, const int* in_sizes, int n_in,
                              void* d_out, int out_size, void* d_ws, size_t ws_size,
                              hipStream_t stream) {
    const float* x    = (const float*)d_in[0];
    const int*   ei   = (const int*)d_in[1];
    const float* W1   = (const float*)d_in[2];
    const float* As1  = (const float*)d_in[3];
    const float* Ad1  = (const float*)d_in[4];
    const float* b1   = (const float*)d_in[5];
    const float* W2   = (const float*)d_in[6];
    const float* As2  = (const float*)d_in[7];
    const float* Ad2  = (const float*)d_in[8];
    const float* b2   = (const float*)d_in[9];
    float* out = (float*)d_out;

    char* p = (char*)d_ws;
    auto alloc = [&](size_t bytes) -> char* {
        char* r = p;
        p += (bytes + 255) & ~(size_t)255;
        return r;
    };
    f16* h1h     = (f16*)alloc((size_t)NNODES * 256 * 2);
    f16* h2h     = (f16*)alloc((size_t)NNODES * 256 * 2);
    float* g2    = (float*)alloc((size_t)NNODES * 32 * 4);
    float* asrc1 = (float*)alloc((size_t)NNODES * 8 * 4);
    float* adst1 = (float*)alloc((size_t)NNODES * 8 * 4);
    float* asrc2 = (float*)alloc((size_t)NNODES * 4);
    float* adst2 = (float*)alloc((size_t)NNODES * 4);
    float* el1   = (float*)alloc((size_t)NEDGES * 8 * 4);
    float* el2   = (float*)alloc((size_t)NEDGES * 4);
    int* deg     = (int*)alloc((size_t)NNODES * 4);
    int* incl    = (int*)alloc((size_t)NNODES * 4);
    int* rowst   = (int*)alloc((size_t)(NNODES + 1) * 4);
    int* cursor  = (int*)alloc((size_t)NNODES * 4);
    int* src_csr = (int*)alloc((size_t)NEDGES * 4);
    int* rowid   = (int*)alloc((size_t)NEDGES * 4);
    int* partial = (int*)alloc(256 * 4);
    int* choff   = (int*)alloc(256 * 4);

    const int EB = NEDGES / 256;           // 3125
    const int NCH = (NNODES + 255) / 256;  // 196

    hipMemsetAsync(deg, 0, (size_t)NNODES * 4, stream);
    k_deg<<<EB, 256, 0, stream>>>(ei, deg);
    k_scanA<<<NCH, 256, 0, stream>>>(deg, incl, partial);
    k_scanB<<<1, 256, 0, stream>>>(partial, choff, NCH);
    k_scanC<<<NCH, 256, 0, stream>>>(deg, incl, choff, rowst, cursor);
    k_scatter<<<EB, 256, 0, stream>>>(ei, cursor, src_csr, rowid);

    k_gemm1<<<dim3((NNODES + 63) / 64, 2), 256, 0, stream>>>(x, W1, h1h);
    k_alpha1<<<NNODES, 256, 0, stream>>>(h1h, As1, Ad1, asrc1, adst1);
    k_e1<<<EB, 256, 0, stream>>>(src_csr, rowid, asrc1, adst1, el1);
    k_agg1<<<NNODES, 256, 0, stream>>>(rowst, src_csr, el1, h1h, b1, h2h);

    k_gemm2<<<(NNODES + 63) / 64, 256, 0, stream>>>(h2h, W2, g2);
    k_alpha2<<<(NNODES + 7) / 8, 256, 0, stream>>>(g2, As2, Ad2, asrc2, adst2);
    k_e2<<<EB, 256, 0, stream>>>(src_csr, rowid, asrc2, adst2, el2);
    k_agg2<<<(NNODES + 7) / 8, 256, 0, stream>>>(rowst, src_csr, el2, g2, b2, out);
}

// Round 4
// 406.924 us; speedup vs baseline: 1.7977x; 1.0759x over previous
//
#include <hip/hip_runtime.h>
#include <math.h>

#define NNODES 50000
#define NEDGES 800000

typedef _Float16 f16;
typedef _Float16 f16x8 __attribute__((ext_vector_type(8)));
typedef _Float16 f16x4 __attribute__((ext_vector_type(4)));
typedef float f32x4 __attribute__((ext_vector_type(4)));

// ---------------- CSR build ----------------

__global__ __launch_bounds__(256) void k_deg(const int* __restrict__ ei, int* __restrict__ deg) {
    int e = blockIdx.x * 256 + threadIdx.x;
    if (e < NEDGES) atomicAdd(&deg[ei[NEDGES + e]], 1);
}

__global__ __launch_bounds__(256) void k_scanA(const int* __restrict__ deg, int* __restrict__ incl,
                                               int* __restrict__ partial) {
    int t = threadIdx.x;
    int i = blockIdx.x * 256 + t;
    int v = (i < NNODES) ? deg[i] : 0;
    int lane = t & 63, wid = t >> 6;
    int s = v;
#pragma unroll
    for (int d = 1; d < 64; d <<= 1) { int u = __shfl_up(s, d, 64); if (lane >= d) s += u; }
    __shared__ int wtot[4];
    if (lane == 63) wtot[wid] = s;
    __syncthreads();
    int off = 0;
    for (int w = 0; w < wid; ++w) off += wtot[w];
    s += off;
    if (i < NNODES) incl[i] = s;
    if (t == 255) partial[blockIdx.x] = s;
}

__global__ __launch_bounds__(256) void k_scanB(const int* __restrict__ partial, int* __restrict__ chunkoff,
                                               int nch) {
    int t = threadIdx.x;
    int v = (t < nch) ? partial[t] : 0;
    int lane = t & 63, wid = t >> 6;
    int s = v;
#pragma unroll
    for (int d = 1; d < 64; d <<= 1) { int u = __shfl_up(s, d, 64); if (lane >= d) s += u; }
    __shared__ int wtot[4];
    if (lane == 63) wtot[wid] = s;
    __syncthreads();
    int off = 0;
    for (int w = 0; w < wid; ++w) off += wtot[w];
    s += off;
    if (t < nch) chunkoff[t] = s - v;  // exclusive
}

__global__ __launch_bounds__(256) void k_scanC(const int* __restrict__ deg, const int* __restrict__ incl,
                                               const int* __restrict__ chunkoff, int* __restrict__ rowst,
                                               int* __restrict__ cursor) {
    int i = blockIdx.x * 256 + threadIdx.x;
    if (i < NNODES) {
        int rs1 = incl[i] + chunkoff[blockIdx.x];
        rowst[i + 1] = rs1;
        cursor[i] = rs1 - deg[i];
        if (i == 0) rowst[0] = 0;
    }
}

// scatter + fused layer-1 edge logits: writes src/rowid in CSR order and
// el1[pos][8] = leakyrelu(as1[s][h] + ad1[d][h])
__global__ __launch_bounds__(256) void k_scatter(const int* __restrict__ ei, int* __restrict__ cursor,
                                                 const float* __restrict__ as1, const float* __restrict__ ad1,
                                                 int* __restrict__ src_csr, int* __restrict__ rowid,
                                                 float* __restrict__ el1) {
    int e = blockIdx.x * 256 + threadIdx.x;
    if (e >= NEDGES) return;
    int s = ei[e], d = ei[NEDGES + e];
    int pos = atomicAdd(&cursor[d], 1);
    src_csr[pos] = s;
    rowid[pos] = d;
    float4 s0 = *(const float4*)(as1 + (size_t)s * 8);
    float4 s1 = *(const float4*)(as1 + (size_t)s * 8 + 4);
    float4 d0 = *(const float4*)(ad1 + (size_t)d * 8);
    float4 d1 = *(const float4*)(ad1 + (size_t)d * 8 + 4);
    float v[8] = {s0.x + d0.x, s0.y + d0.y, s0.z + d0.z, s0.w + d0.w,
                  s1.x + d1.x, s1.y + d1.y, s1.z + d1.z, s1.w + d1.w};
#pragma unroll
    for (int h = 0; h < 8; ++h) { float x = v[h]; v[h] = x > 0.f ? x : 0.2f * x; }
    *(float4*)(el1 + (size_t)pos * 8) = make_float4(v[0], v[1], v[2], v[3]);
    *(float4*)(el1 + (size_t)pos * 8 + 4) = make_float4(v[4], v[5], v[6], v[7]);
}

// ---------------- MFMA GEMMs (fp16 in, fp32 acc) ----------------
// mfma_f32_16x16x32_f16 layouts (lane = tid&63, r = lane&15, quad = lane>>4):
//   A frag a[j] = A[row=r][k=quad*8+j]
//   B frag b[j] = B[k=quad*8+j][col=r]
//   D frag d[i] = D[row=quad*4+i][col=r]

// h1h[N,256](f16) = X[N,128](f32) @ W1[128,256](f32); block: 64 rows x 128 cols.
// Fused: per-row attention dots for the 4 heads this block fully owns.
__global__ __launch_bounds__(256) void k_gemm1(const float* __restrict__ X, const float* __restrict__ W1,
                                               const float* __restrict__ Asrc, const float* __restrict__ Adst,
                                               f16* __restrict__ h1h, float* __restrict__ as1,
                                               float* __restrict__ ad1) {
    __shared__ f16 sA[64 * 136];            // [row][k], stride 136
    __shared__ f16 sB[4 * 128 * 4 * 8];     // ((kc*128 + c)*4 + quad)*8 + j
    int t = threadIdx.x;
    int bm = blockIdx.x * 64, bn = blockIdx.y * 128;
#pragma unroll
    for (int i = 0; i < 8; ++i) {
        int idx = i * 256 + t;
        int row = idx >> 5, c4 = (idx & 31) << 2;
        int gr = bm + row;
        float4 v = make_float4(0.f, 0.f, 0.f, 0.f);
        if (gr < NNODES) v = *(const float4*)(X + (size_t)gr * 128 + c4);
        f16x4 h = {(f16)v.x, (f16)v.y, (f16)v.z, (f16)v.w};
        *(f16x4*)&sA[row * 136 + c4] = h;
    }
#pragma unroll
    for (int i = 0; i < 16; ++i) {
        int idx = i * 256 + t;
        int k = idx >> 5, c4 = (idx & 31) << 2;
        float4 v = *(const float4*)(W1 + (size_t)k * 256 + bn + c4);
        int kc = k >> 5, quad = (k & 31) >> 3, j = k & 7;
        float vv[4] = {v.x, v.y, v.z, v.w};
#pragma unroll
        for (int cc = 0; cc < 4; ++cc)
            sB[(((kc << 7) + c4 + cc) * 4 + quad) * 8 + j] = (f16)vv[cc];
    }
    __syncthreads();
    int lane = t & 63, w = t >> 6;
    int r = lane & 15, quad = lane >> 4;
    int r0 = w * 16;
    f32x4 acc[8];
#pragma unroll
    for (int nt = 0; nt < 8; ++nt) acc[nt] = (f32x4){0.f, 0.f, 0.f, 0.f};
#pragma unroll
    for (int kc = 0; kc < 4; ++kc) {
        f16x8 a = *(f16x8*)&sA[(r0 + r) * 136 + kc * 32 + quad * 8];
#pragma unroll
        for (int nt = 0; nt < 8; ++nt) {
            f16x8 b = *(f16x8*)&sB[(((kc << 7) + nt * 16 + r) * 4 + quad) * 8];
            acc[nt] = __builtin_amdgcn_mfma_f32_16x16x32_f16(a, b, acc[nt], 0, 0, 0);
        }
    }
    // store h1 tile (fp16)
#pragma unroll
    for (int nt = 0; nt < 8; ++nt)
#pragma unroll
        for (int i = 0; i < 4; ++i) {
            int gr = bm + r0 + quad * 4 + i;
            if (gr < NNODES) h1h[(size_t)gr * 256 + bn + nt * 16 + r] = (f16)acc[nt][i];
        }
    // fused alpha: this block owns cols bn..bn+127 = heads (bn>>5)..(bn>>5)+3 completely
    float asv[8], adv[8];
#pragma unroll
    for (int nt = 0; nt < 8; ++nt) {
        asv[nt] = Asrc[bn + nt * 16 + r];
        adv[nt] = Adst[bn + nt * 16 + r];
    }
    int hb = bn >> 5;
#pragma unroll
    for (int i = 0; i < 4; ++i) {
        int gr = bm + r0 + quad * 4 + i;
#pragma unroll
        for (int hl = 0; hl < 4; ++hl) {
            float ps = acc[2 * hl][i] * asv[2 * hl] + acc[2 * hl + 1][i] * asv[2 * hl + 1];
            float pd = acc[2 * hl][i] * adv[2 * hl] + acc[2 * hl + 1][i] * adv[2 * hl + 1];
#pragma unroll
            for (int off = 1; off < 16; off <<= 1) {
                ps += __shfl_xor(ps, off);
                pd += __shfl_xor(pd, off);
            }
            if (r == 0 && gr < NNODES) {
                as1[(size_t)gr * 8 + hb + hl] = ps;
                ad1[(size_t)gr * 8 + hb + hl] = pd;
            }
        }
    }
}

// g[N,32](f32) = h2h[N,256](f16) @ W2[256,32](f32); block: 64 rows.
// Fused: layer-2 attention dots (1 head over all 32 cols).
__global__ __launch_bounds__(256) void k_gemm2(const f16* __restrict__ h2h, const float* __restrict__ W2,
                                               const float* __restrict__ Asrc, const float* __restrict__ Adst,
                                               float* __restrict__ g, float* __restrict__ as2,
                                               float* __restrict__ ad2) {
    __shared__ f16 sA[64 * 264];            // [row][k], stride 264
    __shared__ f16 sB[8 * 32 * 4 * 8];      // ((kc*32 + c)*4 + quad)*8 + j
    int t = threadIdx.x;
    int bm = blockIdx.x * 64;
#pragma unroll
    for (int i = 0; i < 8; ++i) {
        int idx = i * 256 + t;
        int row = idx >> 5, k8 = (idx & 31) << 3;
        int gr = bm + row;
        f16x8 v = {};
        if (gr < NNODES) v = *(const f16x8*)(h2h + (size_t)gr * 256 + k8);
        *(f16x8*)&sA[row * 264 + k8] = v;
    }
#pragma unroll
    for (int i = 0; i < 8; ++i) {
        int idx = i * 256 + t;
        int k = idx >> 3, c4 = (idx & 7) << 2;
        float4 v = *(const float4*)(W2 + (size_t)k * 32 + c4);
        int kc = k >> 5, quad = (k & 31) >> 3, j = k & 7;
        float vv[4] = {v.x, v.y, v.z, v.w};
#pragma unroll
        for (int cc = 0; cc < 4; ++cc)
            sB[(((kc << 5) + c4 + cc) * 4 + quad) * 8 + j] = (f16)vv[cc];
    }
    __syncthreads();
    int lane = t & 63, w = t >> 6;
    int r = lane & 15, quad = lane >> 4;
    int r0 = w * 16;
    f32x4 acc[2];
    acc[0] = (f32x4){0.f, 0.f, 0.f, 0.f};
    acc[1] = (f32x4){0.f, 0.f, 0.f, 0.f};
#pragma unroll
    for (int kc = 0; kc < 8; ++kc) {
        f16x8 a = *(f16x8*)&sA[(r0 + r) * 264 + kc * 32 + quad * 8];
#pragma unroll
        for (int nt = 0; nt < 2; ++nt) {
            f16x8 b = *(f16x8*)&sB[(((kc << 5) + nt * 16 + r) * 4 + quad) * 8];
            acc[nt] = __builtin_amdgcn_mfma_f32_16x16x32_f16(a, b, acc[nt], 0, 0, 0);
        }
    }
#pragma unroll
    for (int nt = 0; nt < 2; ++nt)
#pragma unroll
        for (int i = 0; i < 4; ++i) {
            int gr = bm + r0 + quad * 4 + i;
            if (gr < NNODES) g[(size_t)gr * 32 + nt * 16 + r] = acc[nt][i];
        }
    // fused alpha2
    float as0 = Asrc[r], as16 = Asrc[16 + r];
    float ad0 = Adst[r], ad16 = Adst[16 + r];
#pragma unroll
    for (int i = 0; i < 4; ++i) {
        int gr = bm + r0 + quad * 4 + i;
        float ps = acc[0][i] * as0 + acc[1][i] * as16;
        float pd = acc[0][i] * ad0 + acc[1][i] * ad16;
#pragma unroll
        for (int off = 1; off < 16; off <<= 1) {
            ps += __shfl_xor(ps, off);
            pd += __shfl_xor(pd, off);
        }
        if (r == 0 && gr < NNODES) { as2[gr] = ps; ad2[gr] = pd; }
    }
}

// ---------------- layer-2 edge logits (CSR-position order) ----------------

__global__ __launch_bounds__(256) void k_e2(const int* __restrict__ src_csr, const int* __restrict__ rowid,
                                            const float* __restrict__ as, const float* __restrict__ ad,
                                            float* __restrict__ el) {
    int p = blockIdx.x * 256 + threadIdx.x;
    if (p >= NEDGES) return;
    float x = as[src_csr[p]] + ad[rowid[p]];
    el[p] = x > 0.f ? x : 0.2f * x;
}

// ---------------- fused softmax + aggregate ----------------

// one 256-thread block per node; lane covers 4 contiguous channels (f16x4 load,
// fp32 accumulate); the 4 waves split the edge list stride-4; LDS cross-wave
// reduction; fused bias + ELU + f16 store.
__global__ __launch_bounds__(256) void k_agg1(const int* __restrict__ rowst, const int* __restrict__ src_csr,
                                              const float* __restrict__ el, const f16* __restrict__ h1h,
                                              const float* __restrict__ b1, f16* __restrict__ h2h) {
    int n = blockIdx.x, t = threadIdx.x;
    int w = t >> 6, lane = t & 63;
    __shared__ float sm[8], sinv[8];
    __shared__ float salpha[512];
    __shared__ int ssrc[64];
    __shared__ float sred[3 * 256];
    int s = rowst[n], e = rowst[n + 1];
    // phase 1: per-head max + denom (wave 0; el reads contiguous in CSR order)
    if (t < 64) {
        int head = t & 7, slot = t >> 3;
        float m = -INFINITY;
        for (int j = s + slot; j < e; j += 8) m = fmaxf(m, el[(size_t)j * 8 + head]);
        m = fmaxf(m, __shfl_xor(m, 8));
        m = fmaxf(m, __shfl_xor(m, 16));
        m = fmaxf(m, __shfl_xor(m, 32));
        float sum = 0.f;
        for (int j = s + slot; j < e; j += 8) sum += __expf(el[(size_t)j * 8 + head] - m);
        sum += __shfl_xor(sum, 8);
        sum += __shfl_xor(sum, 16);
        sum += __shfl_xor(sum, 32);
        if (t < 8) { sm[t] = m; sinv[t] = 1.f / (sum + 1e-16f); }
    }
    int head = lane >> 3;       // channel group c0..c0+3 lies in one head
    int c0 = lane << 2;
    f32x4 acc = (f32x4){0.f, 0.f, 0.f, 0.f};
    for (int jc = s; jc < e; jc += 64) {
        int cl = min(64, e - jc);
        __syncthreads();  // protect salpha/ssrc (and sm/sinv on first iter)
        for (int idx = t; idx < cl * 8; idx += 256) {
            int jj = idx >> 3, h = idx & 7;
            salpha[idx] = __expf(el[(size_t)(jc + jj) * 8 + h] - sm[h]) * sinv[h];
        }
        if (t < cl) ssrc[t] = src_csr[jc + t];
        __syncthreads();
        // wave w handles edges j = w, w+4, ... (2-wide unrolled)
        int j = w;
        for (; j + 8 <= cl; j += 8) {
            int s0 = ssrc[j], s1 = ssrc[j + 4];
            float a0 = salpha[j * 8 + head], a1 = salpha[(j + 4) * 8 + head];
            f16x4 v0 = *(const f16x4*)(h1h + (size_t)s0 * 256 + c0);
            f16x4 v1 = *(const f16x4*)(h1h + (size_t)s1 * 256 + c0);
            acc[0] += a0 * (float)v0[0] + a1 * (float)v1[0];
            acc[1] += a0 * (float)v0[1] + a1 * (float)v1[1];
            acc[2] += a0 * (float)v0[2] + a1 * (float)v1[2];
            acc[3] += a0 * (float)v0[3] + a1 * (float)v1[3];
        }
        for (; j < cl; j += 4) {
            int s0 = ssrc[j];
            float a0 = salpha[j * 8 + head];
            f16x4 v0 = *(const f16x4*)(h1h + (size_t)s0 * 256 + c0);
            acc[0] += a0 * (float)v0[0];
            acc[1] += a0 * (float)v0[1];
            acc[2] += a0 * (float)v0[2];
            acc[3] += a0 * (float)v0[3];
        }
    }
    if (w > 0) *(f32x4*)&sred[(w - 1) * 256 + c0] = acc;
    __syncthreads();
    if (w == 0) {
#pragma unroll
        for (int ww = 0; ww < 3; ++ww) {
            f32x4 p = *(f32x4*)&sred[ww * 256 + c0];
            acc[0] += p[0]; acc[1] += p[1]; acc[2] += p[2]; acc[3] += p[3];
        }
        float4 bb = *(const float4*)(b1 + c0);
        float o0 = acc[0] + bb.x, o1 = acc[1] + bb.y, o2 = acc[2] + bb.z, o3 = acc[3] + bb.w;
        o0 = o0 > 0.f ? o0 : __expf(o0) - 1.f;
        o1 = o1 > 0.f ? o1 : __expf(o1) - 1.f;
        o2 = o2 > 0.f ? o2 : __expf(o2) - 1.f;
        o3 = o3 > 0.f ? o3 : __expf(o3) - 1.f;
        f16x4 oh = {(f16)o0, (f16)o1, (f16)o2, (f16)o3};
        *(f16x4*)(h2h + (size_t)n * 256 + c0) = oh;
    }
}

// 8 nodes per block, 32 channels each; fused softmax + aggregate + bias (g fp32)
__global__ __launch_bounds__(256) void k_agg2(const int* __restrict__ rowst, const int* __restrict__ src_csr,
                                              const float* __restrict__ el, const float* __restrict__ g,
                                              const float* __restrict__ b2, float* __restrict__ out) {
    int t = threadIdx.x;
    int n = blockIdx.x * 8 + (t >> 5), c = t & 31;
    if (n >= NNODES) return;
    int s = rowst[n], e = rowst[n + 1];
    float m = -INFINITY;
    for (int j = s + c; j < e; j += 32) m = fmaxf(m, el[j]);
#pragma unroll
    for (int d = 16; d >= 1; d >>= 1) m = fmaxf(m, __shfl_xor(m, d, 32));
    float sum = 0.f;
    for (int j = s + c; j < e; j += 32) sum += __expf(el[j] - m);
#pragma unroll
    for (int d = 16; d >= 1; d >>= 1) sum += __shfl_xor(sum, d, 32);
    float inv = 1.f / (sum + 1e-16f);
    float acc = 0.f;
    int j = s;
    for (; j + 4 <= e; j += 4) {
        int i0 = src_csr[j], i1 = src_csr[j + 1], i2 = src_csr[j + 2], i3 = src_csr[j + 3];
        float a0 = __expf(el[j] - m) * inv,     a1 = __expf(el[j + 1] - m) * inv;
        float a2 = __expf(el[j + 2] - m) * inv, a3 = __expf(el[j + 3] - m) * inv;
        acc += a0 * g[(size_t)i0 * 32 + c] + a1 * g[(size_t)i1 * 32 + c]
             + a2 * g[(size_t)i2 * 32 + c] + a3 * g[(size_t)i3 * 32 + c];
    }
    for (; j < e; ++j) acc += __expf(el[j] - m) * inv * g[(size_t)src_csr[j] * 32 + c];
    out[(size_t)n * 32 + c] = acc + b2[c];
}

// ---------------- launch ----------------

extern "C" void kernel_launch(void* const* d_in, const int* in_sizes, int n_in,
                              void* d_out, int out_size, void* d_ws, size_t ws_size,
                              hipStream_t stream) {
    const float* x    = (const float*)d_in[0];
    const int*   ei   = (const int*)d_in[1];
    const float* W1   = (const float*)d_in[2];
    const float* As1  = (const float*)d_in[3];
    const float* Ad1  = (const float*)d_in[4];
    const float* b1   = (const float*)d_in[5];
    const float* W2   = (const float*)d_in[6];
    const float* As2  = (const float*)d_in[7];
    const float* Ad2  = (const float*)d_in[8];
    const float* b2   = (const float*)d_in[9];
    float* out = (float*)d_out;

    char* p = (char*)d_ws;
    auto alloc = [&](size_t bytes) -> char* {
        char* r = p;
        p += (bytes + 255) & ~(size_t)255;
        return r;
    };
    f16* h1h     = (f16*)alloc((size_t)NNODES * 256 * 2);
    f16* h2h     = (f16*)alloc((size_t)NNODES * 256 * 2);
    float* g2    = (float*)alloc((size_t)NNODES * 32 * 4);
    float* asrc1 = (float*)alloc((size_t)NNODES * 8 * 4);
    float* adst1 = (float*)alloc((size_t)NNODES * 8 * 4);
    float* asrc2 = (float*)alloc((size_t)NNODES * 4);
    float* adst2 = (float*)alloc((size_t)NNODES * 4);
    float* el1   = (float*)alloc((size_t)NEDGES * 8 * 4);
    float* el2   = (float*)alloc((size_t)NEDGES * 4);
    int* deg     = (int*)alloc((size_t)NNODES * 4);
    int* incl    = (int*)alloc((size_t)NNODES * 4);
    int* rowst   = (int*)alloc((size_t)(NNODES + 1) * 4);
    int* cursor  = (int*)alloc((size_t)NNODES * 4);
    int* src_csr = (int*)alloc((size_t)NEDGES * 4);
    int* rowid   = (int*)alloc((size_t)NEDGES * 4);
    int* partial = (int*)alloc(256 * 4);
    int* choff   = (int*)alloc(256 * 4);

    const int EB = NEDGES / 256;           // 3125
    const int NCH = (NNODES + 255) / 256;  // 196

    hipMemsetAsync(deg, 0, (size_t)NNODES * 4, stream);
    k_deg<<<EB, 256, 0, stream>>>(ei, deg);
    k_scanA<<<NCH, 256, 0, stream>>>(deg, incl, partial);
    k_scanB<<<1, 256, 0, stream>>>(partial, choff, NCH);
    k_scanC<<<NCH, 256, 0, stream>>>(deg, incl, choff, rowst, cursor);

    k_gemm1<<<dim3((NNODES + 63) / 64, 2), 256, 0, stream>>>(x, W1, As1, Ad1, h1h, asrc1, adst1);
    k_scatter<<<EB, 256, 0, stream>>>(ei, cursor, asrc1, adst1, src_csr, rowid, el1);
    k_agg1<<<NNODES, 256, 0, stream>>>(rowst, src_csr, el1, h1h, b1, h2h);

    k_gemm2<<<(NNODES + 63) / 64, 256, 0, stream>>>(h2h, W2, As2, Ad2, g2, asrc2, adst2);
    k_e2<<<EB, 256, 0, stream>>>(src_csr, rowid, asrc2, adst2, el2);
    k_agg2<<<(NNODES + 7) / 8, 256, 0, stream>>>(rowst, src_csr, el2, g2, b2, out);
}

// Round 5
// 326.265 us; speedup vs baseline: 2.2422x; 1.2472x over previous
//
#include <hip/hip_runtime.h>
#include <math.h>

#define NNODES 50000
#define NEDGES 800000

typedef _Float16 f16;
typedef _Float16 f16x8 __attribute__((ext_vector_type(8)));
typedef _Float16 f16x4 __attribute__((ext_vector_type(4)));
typedef float f32x4 __attribute__((ext_vector_type(4)));

// ---------------- CSR build ----------------

__global__ __launch_bounds__(256) void k_deg(const int* __restrict__ ei, int* __restrict__ deg) {
    int e = blockIdx.x * 256 + threadIdx.x;
    if (e < NEDGES) atomicAdd(&deg[ei[NEDGES + e]], 1);
}

__global__ __launch_bounds__(256) void k_scanA(const int* __restrict__ deg, int* __restrict__ incl,
                                               int* __restrict__ partial) {
    int t = threadIdx.x;
    int i = blockIdx.x * 256 + t;
    int v = (i < NNODES) ? deg[i] : 0;
    int lane = t & 63, wid = t >> 6;
    int s = v;
#pragma unroll
    for (int d = 1; d < 64; d <<= 1) { int u = __shfl_up(s, d, 64); if (lane >= d) s += u; }
    __shared__ int wtot[4];
    if (lane == 63) wtot[wid] = s;
    __syncthreads();
    int off = 0;
    for (int w = 0; w < wid; ++w) off += wtot[w];
    s += off;
    if (i < NNODES) incl[i] = s;
    if (t == 255) partial[blockIdx.x] = s;
}

__global__ __launch_bounds__(256) void k_scanB(const int* __restrict__ partial, int* __restrict__ chunkoff,
                                               int nch) {
    int t = threadIdx.x;
    int v = (t < nch) ? partial[t] : 0;
    int lane = t & 63, wid = t >> 6;
    int s = v;
#pragma unroll
    for (int d = 1; d < 64; d <<= 1) { int u = __shfl_up(s, d, 64); if (lane >= d) s += u; }
    __shared__ int wtot[4];
    if (lane == 63) wtot[wid] = s;
    __syncthreads();
    int off = 0;
    for (int w = 0; w < wid; ++w) off += wtot[w];
    s += off;
    if (t < nch) chunkoff[t] = s - v;  // exclusive
}

__global__ __launch_bounds__(256) void k_scanC(const int* __restrict__ deg, const int* __restrict__ incl,
                                               const int* __restrict__ chunkoff, int* __restrict__ rowst,
                                               int* __restrict__ cursor) {
    int i = blockIdx.x * 256 + threadIdx.x;
    if (i < NNODES) {
        int rs1 = incl[i] + chunkoff[blockIdx.x];
        rowst[i + 1] = rs1;
        cursor[i] = rs1 - deg[i];
        if (i == 0) rowst[0] = 0;
    }
}

// scatter + fused layer-1 edge logits
__global__ __launch_bounds__(256) void k_scatter(const int* __restrict__ ei, int* __restrict__ cursor,
                                                 const float* __restrict__ as1, const float* __restrict__ ad1,
                                                 int* __restrict__ src_csr, int* __restrict__ rowid,
                                                 float* __restrict__ el1) {
    int e = blockIdx.x * 256 + threadIdx.x;
    if (e >= NEDGES) return;
    int s = ei[e], d = ei[NEDGES + e];
    int pos = atomicAdd(&cursor[d], 1);
    src_csr[pos] = s;
    rowid[pos] = d;
    float4 s0 = *(const float4*)(as1 + (size_t)s * 8);
    float4 s1 = *(const float4*)(as1 + (size_t)s * 8 + 4);
    float4 d0 = *(const float4*)(ad1 + (size_t)d * 8);
    float4 d1 = *(const float4*)(ad1 + (size_t)d * 8 + 4);
    float v[8] = {s0.x + d0.x, s0.y + d0.y, s0.z + d0.z, s0.w + d0.w,
                  s1.x + d1.x, s1.y + d1.y, s1.z + d1.z, s1.w + d1.w};
#pragma unroll
    for (int h = 0; h < 8; ++h) { float x = v[h]; v[h] = x > 0.f ? x : 0.2f * x; }
    *(float4*)(el1 + (size_t)pos * 8) = make_float4(v[0], v[1], v[2], v[3]);
    *(float4*)(el1 + (size_t)pos * 8 + 4) = make_float4(v[4], v[5], v[6], v[7]);
}

// ---------------- weight fragment pre-pack (once per launch) ----------------
// frag addr: (((kc*C + c)*4 + quad)*8 + j), k = kc*32 + quad*8 + j

__global__ __launch_bounds__(256) void k_w1frag(const float* __restrict__ W1, f16* __restrict__ W1f) {
    int id = blockIdx.x * 256 + threadIdx.x;  // 32768 = 128 x 256
    int k = id >> 8, c = id & 255;
    int kc = k >> 5, quad = (k & 31) >> 3, j = k & 7;
    W1f[(((kc << 8) + c) * 4 + quad) * 8 + j] = (f16)W1[id];
}

__global__ __launch_bounds__(256) void k_w2frag(const float* __restrict__ W2, f16* __restrict__ W2f) {
    int id = blockIdx.x * 256 + threadIdx.x;  // 8192 = 256 x 32
    int k = id >> 5, c = id & 31;
    int kc = k >> 5, quad = (k & 31) >> 3, j = k & 7;
    W2f[(((kc << 5) + c) * 4 + quad) * 8 + j] = (f16)W2[id];
}

// ---------------- MFMA GEMMs (fp16 in, fp32 acc) ----------------
// mfma_f32_16x16x32_f16 (lane=tid&63, r=lane&15, quad=lane>>4):
//   A frag a[j]=A[r][quad*8+j]  B frag b[j]=B[quad*8+j][r]  D d[i]=D[quad*4+i][r]

// h1h[N,256](f16) = X @ W1; 64 rows x 128 cols per block; B frags from global.
// Fused: alpha dots for the 4 heads this block owns.
__global__ __launch_bounds__(256) void k_gemm1(const float* __restrict__ X, const f16* __restrict__ W1f,
                                               const float* __restrict__ Asrc, const float* __restrict__ Adst,
                                               f16* __restrict__ h1h, float* __restrict__ as1,
                                               float* __restrict__ ad1) {
    __shared__ f16 sA[64 * 136];
    int t = threadIdx.x;
    int bm = blockIdx.x * 64, bn = blockIdx.y * 128;
#pragma unroll
    for (int i = 0; i < 8; ++i) {
        int idx = i * 256 + t;
        int row = idx >> 5, c4 = (idx & 31) << 2;
        int gr = bm + row;
        float4 v = make_float4(0.f, 0.f, 0.f, 0.f);
        if (gr < NNODES) v = *(const float4*)(X + (size_t)gr * 128 + c4);
        f16x4 h = {(f16)v.x, (f16)v.y, (f16)v.z, (f16)v.w};
        *(f16x4*)&sA[row * 136 + c4] = h;
    }
    __syncthreads();
    int lane = t & 63, w = t >> 6;
    int r = lane & 15, quad = lane >> 4;
    int r0 = w * 16;
    f32x4 acc[8];
#pragma unroll
    for (int nt = 0; nt < 8; ++nt) acc[nt] = (f32x4){0.f, 0.f, 0.f, 0.f};
#pragma unroll
    for (int kc = 0; kc < 4; ++kc) {
        f16x8 a = *(f16x8*)&sA[(r0 + r) * 136 + kc * 32 + quad * 8];
#pragma unroll
        for (int nt = 0; nt < 8; ++nt) {
            f16x8 b = *(const f16x8*)&W1f[(((kc << 8) + bn + nt * 16 + r) * 4 + quad) * 8];
            acc[nt] = __builtin_amdgcn_mfma_f32_16x16x32_f16(a, b, acc[nt], 0, 0, 0);
        }
    }
#pragma unroll
    for (int nt = 0; nt < 8; ++nt)
#pragma unroll
        for (int i = 0; i < 4; ++i) {
            int gr = bm + r0 + quad * 4 + i;
            if (gr < NNODES) h1h[(size_t)gr * 256 + bn + nt * 16 + r] = (f16)acc[nt][i];
        }
    // fused alpha for heads (bn>>5)..(bn>>5)+3
    float asv[8], adv[8];
#pragma unroll
    for (int nt = 0; nt < 8; ++nt) {
        asv[nt] = Asrc[bn + nt * 16 + r];
        adv[nt] = Adst[bn + nt * 16 + r];
    }
    int hb = bn >> 5;
#pragma unroll
    for (int i = 0; i < 4; ++i) {
        int gr = bm + r0 + quad * 4 + i;
#pragma unroll
        for (int hl = 0; hl < 4; ++hl) {
            float ps = acc[2 * hl][i] * asv[2 * hl] + acc[2 * hl + 1][i] * asv[2 * hl + 1];
            float pd = acc[2 * hl][i] * adv[2 * hl] + acc[2 * hl + 1][i] * adv[2 * hl + 1];
#pragma unroll
            for (int off = 1; off < 16; off <<= 1) {
                ps += __shfl_xor(ps, off);
                pd += __shfl_xor(pd, off);
            }
            if (r == 0 && gr < NNODES) {
                as1[(size_t)gr * 8 + hb + hl] = ps;
                ad1[(size_t)gr * 8 + hb + hl] = pd;
            }
        }
    }
}

// g[N,32](f32) = h2h @ W2; 64 rows per block; no LDS, A+B frags from global.
// Fused: layer-2 alpha dots.
__global__ __launch_bounds__(256) void k_gemm2(const f16* __restrict__ h2h, const f16* __restrict__ W2f,
                                               const float* __restrict__ Asrc, const float* __restrict__ Adst,
                                               float* __restrict__ g, float* __restrict__ as2,
                                               float* __restrict__ ad2) {
    int t = threadIdx.x;
    int bm = blockIdx.x * 64;
    int lane = t & 63, w = t >> 6;
    int r = lane & 15, quad = lane >> 4;
    int r0 = w * 16;
    int gra = bm + r0 + r;
    int grac = gra < NNODES ? gra : 0;  // clamp for loads; stores guarded
    f32x4 acc[2];
    acc[0] = (f32x4){0.f, 0.f, 0.f, 0.f};
    acc[1] = (f32x4){0.f, 0.f, 0.f, 0.f};
#pragma unroll
    for (int kc = 0; kc < 8; ++kc) {
        f16x8 a = *(const f16x8*)(h2h + (size_t)grac * 256 + kc * 32 + quad * 8);
#pragma unroll
        for (int nt = 0; nt < 2; ++nt) {
            f16x8 b = *(const f16x8*)&W2f[(((kc << 5) + nt * 16 + r) * 4 + quad) * 8];
            acc[nt] = __builtin_amdgcn_mfma_f32_16x16x32_f16(a, b, acc[nt], 0, 0, 0);
        }
    }
#pragma unroll
    for (int nt = 0; nt < 2; ++nt)
#pragma unroll
        for (int i = 0; i < 4; ++i) {
            int gr = bm + r0 + quad * 4 + i;
            if (gr < NNODES) g[(size_t)gr * 32 + nt * 16 + r] = acc[nt][i];
        }
    float as0 = Asrc[r], as16 = Asrc[16 + r];
    float ad0 = Adst[r], ad16 = Adst[16 + r];
#pragma unroll
    for (int i = 0; i < 4; ++i) {
        int gr = bm + r0 + quad * 4 + i;
        float ps = acc[0][i] * as0 + acc[1][i] * as16;
        float pd = acc[0][i] * ad0 + acc[1][i] * ad16;
#pragma unroll
        for (int off = 1; off < 16; off <<= 1) {
            ps += __shfl_xor(ps, off);
            pd += __shfl_xor(pd, off);
        }
        if (r == 0 && gr < NNODES) { as2[gr] = ps; ad2[gr] = pd; }
    }
}

// ---------------- layer-2 edge logits ----------------

__global__ __launch_bounds__(256) void k_e2(const int* __restrict__ src_csr, const int* __restrict__ rowid,
                                            const float* __restrict__ as, const float* __restrict__ ad,
                                            float* __restrict__ el) {
    int p = blockIdx.x * 256 + threadIdx.x;
    if (p >= NEDGES) return;
    float x = as[src_csr[p]] + ad[rowid[p]];
    el[p] = x > 0.f ? x : 0.2f * x;
}

// ---------------- fused softmax + aggregate ----------------

// Barrier-free: one wave per node, 4 nodes per 256-thread block.
// Stats in-wave over contiguous el (lane = slot*8 + head), then per-lane
// channel coverage c0=lane*4 with on-the-fly alpha and 4-edge-unrolled gather.
__global__ __launch_bounds__(256) void k_agg1(const int* __restrict__ rowst, const int* __restrict__ src_csr,
                                              const float* __restrict__ el, const f16* __restrict__ h1h,
                                              const float* __restrict__ b1, f16* __restrict__ h2h) {
    int w = threadIdx.x >> 6, lane = threadIdx.x & 63;
    int n = blockIdx.x * 4 + w;
    int s = rowst[n], e = rowst[n + 1];
    // stats: lane = slot*8 + head
    int head8 = lane & 7, slot = lane >> 3;
    float m = -INFINITY;
    for (int j = s + slot; j < e; j += 8) m = fmaxf(m, el[(size_t)j * 8 + head8]);
    m = fmaxf(m, __shfl_xor(m, 8));
    m = fmaxf(m, __shfl_xor(m, 16));
    m = fmaxf(m, __shfl_xor(m, 32));
    float sum = 0.f;
    for (int j = s + slot; j < e; j += 8) sum += __expf(el[(size_t)j * 8 + head8] - m);
    sum += __shfl_xor(sum, 8);
    sum += __shfl_xor(sum, 16);
    sum += __shfl_xor(sum, 32);
    float inv = 1.f / (sum + 1e-16f);
    // remap: lane covers channels c0..c0+3 (head = lane>>3); lane L'=lane>>3 holds head L'
    int hm = lane >> 3;
    float mq = __shfl(m, hm);
    float invq = __shfl(inv, hm);
    int c0 = lane << 2;
    const f16* hp = h1h + c0;
    f32x4 acc = (f32x4){0.f, 0.f, 0.f, 0.f};
    int j = s;
    int e4 = s + ((e - s) & ~3);
    for (; j < e4; j += 4) {
        int s0 = src_csr[j], s1 = src_csr[j + 1], s2 = src_csr[j + 2], s3 = src_csr[j + 3];
        float l0 = el[(size_t)j * 8 + hm],       l1 = el[(size_t)(j + 1) * 8 + hm];
        float l2 = el[(size_t)(j + 2) * 8 + hm], l3 = el[(size_t)(j + 3) * 8 + hm];
        f16x4 v0 = *(const f16x4*)(hp + (size_t)s0 * 256);
        f16x4 v1 = *(const f16x4*)(hp + (size_t)s1 * 256);
        f16x4 v2 = *(const f16x4*)(hp + (size_t)s2 * 256);
        f16x4 v3 = *(const f16x4*)(hp + (size_t)s3 * 256);
        float a0 = __expf(l0 - mq) * invq, a1 = __expf(l1 - mq) * invq;
        float a2 = __expf(l2 - mq) * invq, a3 = __expf(l3 - mq) * invq;
        acc[0] += a0 * (float)v0[0] + a1 * (float)v1[0] + a2 * (float)v2[0] + a3 * (float)v3[0];
        acc[1] += a0 * (float)v0[1] + a1 * (float)v1[1] + a2 * (float)v2[1] + a3 * (float)v3[1];
        acc[2] += a0 * (float)v0[2] + a1 * (float)v1[2] + a2 * (float)v2[2] + a3 * (float)v3[2];
        acc[3] += a0 * (float)v0[3] + a1 * (float)v1[3] + a2 * (float)v2[3] + a3 * (float)v3[3];
    }
    for (; j < e; ++j) {
        int s0 = src_csr[j];
        float a0 = __expf(el[(size_t)j * 8 + hm] - mq) * invq;
        f16x4 v0 = *(const f16x4*)(hp + (size_t)s0 * 256);
        acc[0] += a0 * (float)v0[0];
        acc[1] += a0 * (float)v0[1];
        acc[2] += a0 * (float)v0[2];
        acc[3] += a0 * (float)v0[3];
    }
    float4 bb = *(const float4*)(b1 + c0);
    float o0 = acc[0] + bb.x, o1 = acc[1] + bb.y, o2 = acc[2] + bb.z, o3 = acc[3] + bb.w;
    o0 = o0 > 0.f ? o0 : __expf(o0) - 1.f;
    o1 = o1 > 0.f ? o1 : __expf(o1) - 1.f;
    o2 = o2 > 0.f ? o2 : __expf(o2) - 1.f;
    o3 = o3 > 0.f ? o3 : __expf(o3) - 1.f;
    f16x4 oh = {(f16)o0, (f16)o1, (f16)o2, (f16)o3};
    *(f16x4*)(h2h + (size_t)n * 256 + c0) = oh;
}

// 8 nodes per block, 32 channels each
__global__ __launch_bounds__(256) void k_agg2(const int* __restrict__ rowst, const int* __restrict__ src_csr,
                                              const float* __restrict__ el, const float* __restrict__ g,
                                              const float* __restrict__ b2, float* __restrict__ out) {
    int t = threadIdx.x;
    int n = blockIdx.x * 8 + (t >> 5), c = t & 31;
    if (n >= NNODES) return;
    int s = rowst[n], e = rowst[n + 1];
    float m = -INFINITY;
    for (int j = s + c; j < e; j += 32) m = fmaxf(m, el[j]);
#pragma unroll
    for (int d = 16; d >= 1; d >>= 1) m = fmaxf(m, __shfl_xor(m, d, 32));
    float sum = 0.f;
    for (int j = s + c; j < e; j += 32) sum += __expf(el[j] - m);
#pragma unroll
    for (int d = 16; d >= 1; d >>= 1) sum += __shfl_xor(sum, d, 32);
    float inv = 1.f / (sum + 1e-16f);
    float acc = 0.f;
    int j = s;
    for (; j + 4 <= e; j += 4) {
        int i0 = src_csr[j], i1 = src_csr[j + 1], i2 = src_csr[j + 2], i3 = src_csr[j + 3];
        float a0 = __expf(el[j] - m) * inv,     a1 = __expf(el[j + 1] - m) * inv;
        float a2 = __expf(el[j + 2] - m) * inv, a3 = __expf(el[j + 3] - m) * inv;
        acc += a0 * g[(size_t)i0 * 32 + c] + a1 * g[(size_t)i1 * 32 + c]
             + a2 * g[(size_t)i2 * 32 + c] + a3 * g[(size_t)i3 * 32 + c];
    }
    for (; j < e; ++j) acc += __expf(el[j] - m) * inv * g[(size_t)src_csr[j] * 32 + c];
    out[(size_t)n * 32 + c] = acc + b2[c];
}

// ---------------- launch ----------------

extern "C" void kernel_launch(void* const* d_in, const int* in_sizes, int n_in,
                              void* d_out, int out_size, void* d_ws, size_t ws_size,
                              hipStream_t stream) {
    const float* x    = (const float*)d_in[0];
    const int*   ei   = (const int*)d_in[1];
    const float* W1   = (const float*)d_in[2];
    const float* As1  = (const float*)d_in[3];
    const float* Ad1  = (const float*)d_in[4];
    const float* b1   = (const float*)d_in[5];
    const float* W2   = (const float*)d_in[6];
    const float* As2  = (const float*)d_in[7];
    const float* Ad2  = (const float*)d_in[8];
    const float* b2   = (const float*)d_in[9];
    float* out = (float*)d_out;

    char* p = (char*)d_ws;
    auto alloc = [&](size_t bytes) -> char* {
        char* r = p;
        p += (bytes + 255) & ~(size_t)255;
        return r;
    };
    f16* h1h     = (f16*)alloc((size_t)NNODES * 256 * 2);
    f16* h2h     = (f16*)alloc((size_t)NNODES * 256 * 2);
    f16* W1f     = (f16*)alloc((size_t)128 * 256 * 2);
    f16* W2f     = (f16*)alloc((size_t)256 * 32 * 2);
    float* g2    = (float*)alloc((size_t)NNODES * 32 * 4);
    float* asrc1 = (float*)alloc((size_t)NNODES * 8 * 4);
    float* adst1 = (float*)alloc((size_t)NNODES * 8 * 4);
    float* asrc2 = (float*)alloc((size_t)NNODES * 4);
    float* adst2 = (float*)alloc((size_t)NNODES * 4);
    float* el1   = (float*)alloc((size_t)NEDGES * 8 * 4);
    float* el2   = (float*)alloc((size_t)NEDGES * 4);
    int* deg     = (int*)alloc((size_t)NNODES * 4);
    int* incl    = (int*)alloc((size_t)NNODES * 4);
    int* rowst   = (int*)alloc((size_t)(NNODES + 1) * 4);
    int* cursor  = (int*)alloc((size_t)NNODES * 4);
    int* src_csr = (int*)alloc((size_t)NEDGES * 4);
    int* rowid   = (int*)alloc((size_t)NEDGES * 4);
    int* partial = (int*)alloc(256 * 4);
    int* choff   = (int*)alloc(256 * 4);

    const int EB = NEDGES / 256;           // 3125
    const int NCH = (NNODES + 255) / 256;  // 196

    hipMemsetAsync(deg, 0, (size_t)NNODES * 4, stream);
    k_deg<<<EB, 256, 0, stream>>>(ei, deg);
    k_scanA<<<NCH, 256, 0, stream>>>(deg, incl, partial);
    k_scanB<<<1, 256, 0, stream>>>(partial, choff, NCH);
    k_scanC<<<NCH, 256, 0, stream>>>(deg, incl, choff, rowst, cursor);
    k_w1frag<<<128, 256, 0, stream>>>(W1, W1f);
    k_w2frag<<<32, 256, 0, stream>>>(W2, W2f);

    k_gemm1<<<dim3((NNODES + 63) / 64, 2), 256, 0, stream>>>(x, W1f, As1, Ad1, h1h, asrc1, adst1);
    k_scatter<<<EB, 256, 0, stream>>>(ei, cursor, asrc1, adst1, src_csr, rowid, el1);
    k_agg1<<<NNODES / 4, 256, 0, stream>>>(rowst, src_csr, el1, h1h, b1, h2h);

    k_gemm2<<<(NNODES + 63) / 64, 256, 0, stream>>>(h2h, W2f, As2, Ad2, g2, asrc2, adst2);
    k_e2<<<EB, 256, 0, stream>>>(src_csr, rowid, asrc2, adst2, el2);
    k_agg2<<<(NNODES + 7) / 8, 256, 0, stream>>>(rowst, src_csr, el2, g2, b2, out);
}